// Round 4
// baseline (580.927 us; speedup 1.0000x reference)
//
#include <hip/hip_runtime.h>

#define T_ 1024
#define D_ 1024
#define B_ 4
#define H_ 16
#define DH_ 64
#define M_ (B_*T_)                 // 4096
#define NEG_ (-4294967295.0f)

typedef __attribute__((ext_vector_type(8))) short bf16x8;
typedef __attribute__((ext_vector_type(4))) float f32x4;

__device__ __forceinline__ float b2f(unsigned short u) {
    union { unsigned int i; float f; } v; v.i = ((unsigned int)u) << 16; return v.f;
}
__device__ __forceinline__ unsigned short f2b(float f) {
    unsigned int x = __float_as_uint(f);
    return (unsigned short)((x + 0x7fffu + ((x >> 16) & 1u)) >> 16);
}

typedef const unsigned int __attribute__((address_space(1)))* gas_p;
typedef unsigned int __attribute__((address_space(3)))* las_p;
__device__ __forceinline__ void gl_lds16(const void* g, void* l) {
    __builtin_amdgcn_global_load_lds((gas_p)g, (las_p)l, 16, 0, 0);
}

// ---------------- conv: A3 rows 0..4095 = [hi|lo|hi](q_in) ----------------
__global__ __launch_bounds__(256) void conv_a3(const float* __restrict__ q,
                                               const float* __restrict__ peq,
                                               unsigned short* __restrict__ A3)
{
    int i = blockIdx.x * 256 + threadIdx.x;
    int m = i >> 8, c4 = (i & 255) << 2;
    float4 qv = *(const float4*)(q + (size_t)m * D_ + c4);
    float4 p  = *(const float4*)(peq + (size_t)(m & (T_-1)) * D_ + c4);
    float x[4] = { qv.x + 32.f*p.x, qv.y + 32.f*p.y, qv.z + 32.f*p.z, qv.w + 32.f*p.w };
    ushort4 h, l;
    h.x = f2b(x[0]); h.y = f2b(x[1]); h.z = f2b(x[2]); h.w = f2b(x[3]);
    l.x = f2b(x[0] - b2f(h.x)); l.y = f2b(x[1] - b2f(h.y));
    l.z = f2b(x[2] - b2f(h.z)); l.w = f2b(x[3] - b2f(h.w));
    size_t base = (size_t)m * 3072;
    *(ushort4*)(A3 + base + c4) = h;
    *(ushort4*)(A3 + base + 1024 + c4) = l;
    *(ushort4*)(A3 + base + 2048 + c4) = h;
}

// ---------------- conv: A3 rows 4096..5119 = [hi|lo|hi](32*pe_k) ----------------
__global__ __launch_bounds__(256) void conv_pe3(const float* __restrict__ pek,
                                                unsigned short* __restrict__ A3)
{
    int i = blockIdx.x * 256 + threadIdx.x;
    int m = i >> 8, c4 = (i & 255) << 2;
    float4 p = *(const float4*)(pek + (size_t)m * D_ + c4);
    float x[4] = { 32.f*p.x, 32.f*p.y, 32.f*p.z, 32.f*p.w };
    ushort4 h, l;
    h.x = f2b(x[0]); h.y = f2b(x[1]); h.z = f2b(x[2]); h.w = f2b(x[3]);
    l.x = f2b(x[0] - b2f(h.x)); l.y = f2b(x[1] - b2f(h.y));
    l.z = f2b(x[2] - b2f(h.z)); l.w = f2b(x[3] - b2f(h.w));
    size_t base = (size_t)(m + 4096) * 3072;
    *(ushort4*)(A3 + base + c4) = h;
    *(ushort4*)(A3 + base + 1024 + c4) = l;
    *(ushort4*)(A3 + base + 2048 + c4) = h;
}

// ---------------- conv: q16 = hi(q_in) ----------------
__global__ __launch_bounds__(256) void conv_q16(const float* __restrict__ q,
                                                const float* __restrict__ peq,
                                                unsigned short* __restrict__ q16)
{
    int i = blockIdx.x * 256 + threadIdx.x;
    int m = i >> 8, c4 = (i & 255) << 2;
    float4 qv = *(const float4*)(q + (size_t)m * D_ + c4);
    float4 p  = *(const float4*)(peq + (size_t)(m & (T_-1)) * D_ + c4);
    ushort4 h;
    h.x = f2b(qv.x + 32.f*p.x); h.y = f2b(qv.y + 32.f*p.y);
    h.z = f2b(qv.z + 32.f*p.z); h.w = f2b(qv.w + 32.f*p.w);
    *(ushort4*)(q16 + (size_t)m * 1024 + c4) = h;
}

// ---------------- conv: [Wq|Wk] -> B3 rows n in [0,2048), [hi|hi|lo], ld 3072 ----------------
__global__ __launch_bounds__(256) void conv_w3(const float* __restrict__ Wq,
                                               const float* __restrict__ Wk,
                                               unsigned short* __restrict__ B3)
{
    __shared__ float t[32][33];
    const float* W = blockIdx.z ? Wk : Wq;
    int k0 = blockIdx.y * 32, n0 = blockIdx.x * 32;
    int r = threadIdx.x >> 5, c = threadIdx.x & 31;
    #pragma unroll
    for (int rr = 0; rr < 4; ++rr)
        t[r + 8*rr][c] = W[(size_t)(k0 + r + 8*rr) * 1024 + n0 + c];
    __syncthreads();
    #pragma unroll
    for (int rr = 0; rr < 4; ++rr) {
        float v = t[c][r + 8*rr];
        unsigned short h = f2b(v);
        unsigned short l = f2b(v - b2f(h));
        size_t o = (size_t)(blockIdx.z * 1024 + n0 + r + 8*rr) * 3072 + k0 + c;
        B3[o] = h; B3[o + 1024] = h; B3[o + 2048] = l;
    }
}

// ---------------- conv: WT[n][k] = bf16(W[k][n]) ----------------
__global__ __launch_bounds__(256) void conv_wT(const float* __restrict__ W,
                                               unsigned short* __restrict__ WT,
                                               int K, int N)
{
    __shared__ float t[32][33];
    int k0 = blockIdx.y * 32, n0 = blockIdx.x * 32;
    int r = threadIdx.x >> 5, c = threadIdx.x & 31;
    #pragma unroll
    for (int rr = 0; rr < 4; ++rr)
        t[r + 8*rr][c] = W[(size_t)(k0 + r + 8*rr) * N + n0 + c];
    __syncthreads();
    #pragma unroll
    for (int rr = 0; rr < 4; ++rr)
        WT[(size_t)(n0 + r + 8*rr) * K + k0 + c] = f2b(t[c][r + 8*rr]);
}

// ---------------- 2-phase double-buffered bf16 MFMA GEMM ----------------
// C = A[M][lda] @ B_T[N][ldb]^T.  BM x 128 tile, BK=64, 4 waves.
// CONVA: A is f32 (+peA row-broadcast add), converted during reg-staged LDS write.
// flags: 1 relu | 8 store-f32 | 16 store-bf16 | 32 stacked-QK epilogue
template<int BM, bool CONVA>
__global__ __launch_bounds__(256) void gemm_mfma(
    const void* __restrict__ Ap, int lda,
    const unsigned short* __restrict__ B, int ldb, int K,
    const float* __restrict__ peA,
    float* __restrict__ outf, float* __restrict__ outf2, float* __restrict__ outp,
    unsigned short* __restrict__ outh, int N, int flags)
{
    constexpr int LOGBM = (BM == 128) ? 7 : 6;
    constexpr int WN = (BM == 128) ? 2 : 4;     // waves along n
    constexpr int FN = 8 / WN;                   // n-frags per wave
    constexpr int NA = BM / 32;                  // A chunks per thread
    __shared__ __align__(16) unsigned short As[2][BM * 64];
    __shared__ __align__(16) unsigned short Bs[2][128 * 64];
    const int tid = threadIdx.x;
    const int m0 = blockIdx.y * BM, n0 = blockIdx.x << 7;
    if ((flags & 32) && m0 >= 4096 && n0 < 1024) return;   // pe-rows x Q-cols: garbage
    const int lane = tid & 63, wave = tid >> 6;
    const int wm = (wave / WN) * 64;
    const int wn = (wave % WN) * (128 / WN);
    const int rl = lane & 15, kg = lane >> 4;

    int ca[NA]; const unsigned short* gA[NA]; const float* gAf[NA]; const float* gAp[NA];
    #pragma unroll
    for (int i = 0; i < NA; ++i) {
        int c = i * 256 + tid;
        ca[i] = c * 8;
        int row = c & (BM - 1), k8 = c >> LOGBM;
        if constexpr (CONVA) {
            gAf[i] = (const float*)Ap + (size_t)(m0 + row) * lda + k8 * 8;
            gAp[i] = peA + (size_t)((m0 + row) & (T_ - 1)) * lda + k8 * 8;
        } else {
            gA[i]  = (const unsigned short*)Ap + (size_t)(m0 + row) * lda + k8 * 8;
        }
    }
    int cb[4]; const unsigned short* gB[4];
    #pragma unroll
    for (int i = 0; i < 4; ++i) {
        int c = i * 256 + tid;
        cb[i] = c * 8;
        gB[i] = B + (size_t)(n0 + (c & 127)) * ldb + (c >> 7) * 8;
    }

    f32x4 acc[4][FN];
    #pragma unroll
    for (int i = 0; i < 4; ++i)
        #pragma unroll
        for (int j = 0; j < FN; ++j) {
            acc[i][j][0] = 0.f; acc[i][j][1] = 0.f;
            acc[i][j][2] = 0.f; acc[i][j][3] = 0.f;
        }

    float4 xa[NA][2], xp[NA][2];
    const int NT = K >> 6;

    // ---- prologue: stage tile 0 into buf 0
    #pragma unroll
    for (int i = 0; i < 4; ++i) gl_lds16(gB[i], &Bs[0][cb[i]]);
    if constexpr (CONVA) {
        #pragma unroll
        for (int i = 0; i < NA; ++i) {
            xa[i][0] = *(const float4*)(gAf[i]);     xa[i][1] = *(const float4*)(gAf[i] + 4);
            xp[i][0] = *(const float4*)(gAp[i]);     xp[i][1] = *(const float4*)(gAp[i] + 4);
        }
        #pragma unroll
        for (int i = 0; i < NA; ++i) {
            ushort4 u0, u1;
            u0.x = f2b(xa[i][0].x + xp[i][0].x); u0.y = f2b(xa[i][0].y + xp[i][0].y);
            u0.z = f2b(xa[i][0].z + xp[i][0].z); u0.w = f2b(xa[i][0].w + xp[i][0].w);
            u1.x = f2b(xa[i][1].x + xp[i][1].x); u1.y = f2b(xa[i][1].y + xp[i][1].y);
            u1.z = f2b(xa[i][1].z + xp[i][1].z); u1.w = f2b(xa[i][1].w + xp[i][1].w);
            *(ushort4*)&As[0][ca[i]] = u0;
            *(ushort4*)&As[0][ca[i] + 4] = u1;
        }
    } else {
        #pragma unroll
        for (int i = 0; i < NA; ++i) gl_lds16(gA[i], &As[0][ca[i]]);
    }
    __syncthreads();

    int cur = 0;
    for (int t = 0; t < NT; ++t) {
        const int k0n = (t + 1) << 6;
        const bool pre = (t + 1 < NT);
        // ---- issue next-tile loads (overlap with current compute)
        if (pre) {
            #pragma unroll
            for (int i = 0; i < 4; ++i) gl_lds16(gB[i] + k0n, &Bs[cur ^ 1][cb[i]]);
            if constexpr (CONVA) {
                #pragma unroll
                for (int i = 0; i < NA; ++i) {
                    xa[i][0] = *(const float4*)(gAf[i] + k0n);
                    xa[i][1] = *(const float4*)(gAf[i] + k0n + 4);
                    xp[i][0] = *(const float4*)(gAp[i] + k0n);
                    xp[i][1] = *(const float4*)(gAp[i] + k0n + 4);
                }
            } else {
                #pragma unroll
                for (int i = 0; i < NA; ++i) gl_lds16(gA[i] + k0n, &As[cur ^ 1][ca[i]]);
            }
        }
        // ---- compute current tile
        bf16x8 av[2][4], bv[2][FN];
        #pragma unroll
        for (int tt = 0; tt < 2; ++tt) {
            #pragma unroll
            for (int f = 0; f < 4; ++f)
                av[tt][f] = *(const bf16x8*)&As[cur][(((tt*4 + kg) << LOGBM) + wm + (f << 4) + rl) * 8];
            #pragma unroll
            for (int f = 0; f < FN; ++f)
                bv[tt][f] = *(const bf16x8*)&Bs[cur][(((tt*4 + kg) << 7) + wn + (f << 4) + rl) * 8];
        }
        #pragma unroll
        for (int fm = 0; fm < 4; ++fm)
            #pragma unroll
            for (int fn = 0; fn < FN; ++fn) {
                acc[fm][fn] = __builtin_amdgcn_mfma_f32_16x16x32_bf16(av[0][fm], bv[0][fn], acc[fm][fn], 0, 0, 0);
                acc[fm][fn] = __builtin_amdgcn_mfma_f32_16x16x32_bf16(av[1][fm], bv[1][fn], acc[fm][fn], 0, 0, 0);
            }
        if (pre) {
            if constexpr (CONVA) {
                #pragma unroll
                for (int i = 0; i < NA; ++i) {
                    ushort4 u0, u1;
                    u0.x = f2b(xa[i][0].x + xp[i][0].x); u0.y = f2b(xa[i][0].y + xp[i][0].y);
                    u0.z = f2b(xa[i][0].z + xp[i][0].z); u0.w = f2b(xa[i][0].w + xp[i][0].w);
                    u1.x = f2b(xa[i][1].x + xp[i][1].x); u1.y = f2b(xa[i][1].y + xp[i][1].y);
                    u1.z = f2b(xa[i][1].z + xp[i][1].z); u1.w = f2b(xa[i][1].w + xp[i][1].w);
                    *(ushort4*)&As[cur ^ 1][ca[i]] = u0;
                    *(ushort4*)&As[cur ^ 1][ca[i] + 4] = u1;
                }
            }
        }
        __syncthreads();
        cur ^= 1;
    }

    // ---- epilogue: C/D layout col=lane&15, row=(lane>>4)*4+reg
    #pragma unroll
    for (int fm = 0; fm < 4; ++fm) {
        int row = m0 + wm + (fm << 4) + (kg << 2);
        #pragma unroll
        for (int fn = 0; fn < FN; ++fn) {
            int col = n0 + wn + (fn << 4) + rl;
            #pragma unroll
            for (int r = 0; r < 4; ++r) {
                float x = acc[fm][fn][r];
                int rr = row + r;
                if (flags & 32) {
                    if (rr < 4096) {
                        if (col < 1024) outf[(size_t)rr * 1024 + col] = x;
                        else            outf2[(size_t)rr * 1024 + (col - 1024)] = x;
                    } else if (col >= 1024) {
                        outp[(size_t)(rr - 4096) * 1024 + (col - 1024)] = x;
                    }
                } else {
                    size_t idx = (size_t)rr * N + col;
                    if (flags & 1)  x = fmaxf(x, 0.f);
                    if (flags & 8)  outf[idx] = x;
                    if (flags & 16) outh[idx] = f2b(x);
                }
            }
        }
    }
}

// ---------------- flash-style fp32 attention; residual in bf16 in-place ----------------
__global__ __launch_bounds__(256) void attn(const float* __restrict__ Q,
                                            const float* __restrict__ Kraw,
                                            const float* __restrict__ pekw,
                                            const float* __restrict__ Vp,
                                            unsigned short* __restrict__ q16,
                                            const int* __restrict__ qlens,
                                            const int* __restrict__ klens)
{
    __shared__ __align__(16) float QsT[64][68];
    __shared__ __align__(16) float KP[64][68];
    __shared__ __align__(16) float Vs[64][68];
    __shared__ float rowm[64], rowl[64], rowfac[64];

    const int tid = threadIdx.x;
    const int qt = blockIdx.x, h = blockIdx.y, b = blockIdx.z;
    const int qbase = qt * 64;
    const int qlen = qlens[b], klen = klens[b];
    if (qbase >= qlen) return;

    {
        int r = tid >> 2;
        int cc = (tid & 3) * 16;
        const float* src = Q + ((size_t)(b * T_ + qbase + r)) * D_ + h * DH_ + cc;
        #pragma unroll
        for (int u = 0; u < 4; ++u) {
            float4 v = *(const float4*)(src + u * 4);
            QsT[cc + u*4 + 0][r] = v.x; QsT[cc + u*4 + 1][r] = v.y;
            QsT[cc + u*4 + 2][r] = v.z; QsT[cc + u*4 + 3][r] = v.w;
        }
    }
    if (tid < 64) { rowm[tid] = -3.0e38f; rowl[tid] = 0.f; }

    const int q0 = (tid >> 4) * 4;
    const int c0 = (tid & 15) * 4;
    float acc[4][4] = {};

    const int nt = (klen == 1) ? (T_/64) : ((klen + 63) >> 6);
    for (int kb = 0; kb < nt; ++kb) {
        const int kbase = kb * 64;
        __syncthreads();
        {
            int r = tid >> 2;
            int cc = (tid & 3) * 16;
            const float* ksrc = Kraw + ((size_t)(b * T_ + kbase + r)) * D_ + h * DH_ + cc;
            const float* psrc = pekw + (size_t)(kbase + r) * D_ + h * DH_ + cc;
            const float* vsrc = Vp + ((size_t)(b * T_ + kbase + r)) * D_ + h * DH_ + cc;
            #pragma unroll
            for (int u = 0; u < 4; ++u) {
                float4 v = *(const float4*)(ksrc + u * 4);
                float4 pv = *(const float4*)(psrc + u * 4);
                v.x += pv.x; v.y += pv.y; v.z += pv.z; v.w += pv.w;
                KP[cc + u*4 + 0][r] = v.x; KP[cc + u*4 + 1][r] = v.y;
                KP[cc + u*4 + 2][r] = v.z; KP[cc + u*4 + 3][r] = v.w;
                *(float4*)&Vs[r][cc + u*4] = *(const float4*)(vsrc + u * 4);
            }
        }
        __syncthreads();
        float s[4][4] = {};
        #pragma unroll 8
        for (int d = 0; d < 64; ++d) {
            float4 qa = *(float4*)&QsT[d][q0];
            float4 ka = *(float4*)&KP[d][c0];
            float qv[4] = {qa.x, qa.y, qa.z, qa.w};
            float kv[4] = {ka.x, ka.y, ka.z, ka.w};
            #pragma unroll
            for (int i = 0; i < 4; ++i)
                #pragma unroll
                for (int j = 0; j < 4; ++j) s[i][j] += qv[i] * kv[j];
        }
        __syncthreads();
        #pragma unroll
        for (int i = 0; i < 4; ++i) {
            int gq = qbase + q0 + i;
            #pragma unroll
            for (int j = 0; j < 4; ++j) {
                int gk = kbase + c0 + j;
                float v = s[i][j] * 0.125f;
                if (gk >= klen || gk == gq) v = NEG_;
                KP[c0 + j][q0 + i] = v;
            }
        }
        __syncthreads();
        {
            int q = tid >> 2, g = tid & 3;
            float mx = -3.0e38f;
            #pragma unroll
            for (int kk = 0; kk < 16; ++kk) mx = fmaxf(mx, KP[g * 16 + kk][q]);
            mx = fmaxf(mx, __shfl_xor(mx, 1));
            mx = fmaxf(mx, __shfl_xor(mx, 2));
            float mold = rowm[q];
            float mnew = fmaxf(mold, mx);
            float sum = 0.f;
            #pragma unroll
            for (int kk = 0; kk < 16; ++kk) {
                int k = g * 16 + kk;
                float p = __expf(KP[k][q] - mnew);
                KP[k][q] = p;
                sum += p;
            }
            sum += __shfl_xor(sum, 1);
            sum += __shfl_xor(sum, 2);
            float fac = __expf(mold - mnew);
            if (g == 0) { rowm[q] = mnew; rowl[q] = rowl[q] * fac + sum; rowfac[q] = fac; }
        }
        __syncthreads();
        {
            float f[4];
            #pragma unroll
            for (int i = 0; i < 4; ++i) f[i] = rowfac[q0 + i];
            #pragma unroll
            for (int i = 0; i < 4; ++i)
                #pragma unroll
                for (int j = 0; j < 4; ++j) acc[i][j] *= f[i];
            #pragma unroll 8
            for (int k = 0; k < 64; ++k) {
                float4 pa = *(float4*)&KP[k][q0];
                float4 vb = *(float4*)&Vs[k][c0];
                float pv[4] = {pa.x, pa.y, pa.z, pa.w};
                float vv[4] = {vb.x, vb.y, vb.z, vb.w};
                #pragma unroll
                for (int i = 0; i < 4; ++i)
                    #pragma unroll
                    for (int j = 0; j < 4; ++j) acc[i][j] += pv[i] * vv[j];
            }
        }
    }
    #pragma unroll
    for (int i = 0; i < 4; ++i) {
        int gq = qbase + q0 + i;
        float qm = (gq < qlen) ? 1.f : 0.f;
        float invl = qm / rowl[q0 + i];
        size_t off = ((size_t)(b * T_ + gq)) * D_ + h * DH_ + c0;
        ushort4 r4 = *(const ushort4*)(q16 + off);
        ushort4 o;
        o.x = f2b(acc[i][0] * invl + b2f(r4.x));
        o.y = f2b(acc[i][1] * invl + b2f(r4.y));
        o.z = f2b(acc[i][2] * invl + b2f(r4.z));
        o.w = f2b(acc[i][3] * invl + b2f(r4.w));
        *(ushort4*)(q16 + off) = o;
    }
}

// ---------------- mean over T of bf16 [4][1024][X] -> f32 [4][X] ----------------
__global__ __launch_bounds__(256) void mean16(const unsigned short* __restrict__ X,
                                              float* __restrict__ out, int Xdim)
{
    __shared__ float red[4][128];
    int tid = threadIdx.x;
    int b = blockIdx.y;
    int dbase = blockIdx.x * 128;
    int tq = tid >> 6, dd = tid & 63;
    int d = dbase + dd * 2;
    const unsigned short* p = X + ((size_t)b * T_ + tq * 256) * Xdim + d;
    float s0 = 0.f, s1 = 0.f;
    for (int t = 0; t < 256; ++t) {
        ushort2 v = *(const ushort2*)(p + (size_t)t * Xdim);
        s0 += b2f(v.x); s1 += b2f(v.y);
    }
    red[tq][dd*2] = s0; red[tq][dd*2 + 1] = s1;
    __syncthreads();
    if (tq == 0) {
        float a = red[0][dd*2] + red[1][dd*2] + red[2][dd*2] + red[3][dd*2];
        float c = red[0][dd*2+1] + red[1][dd*2+1] + red[2][dd*2+1] + red[3][dd*2+1];
        out[(size_t)b * Xdim + d]     = a * (1.f/1024.f);
        out[(size_t)b * Xdim + d + 1] = c * (1.f/1024.f);
    }
}

// ---------------- out[b][d] = Mres[b][d] + sum_j Hm[b][j]*fw2[j][d] ----------------
__global__ __launch_bounds__(256) void final_out(const float* __restrict__ Mres,
                                                 const float* __restrict__ Hm,
                                                 const float* __restrict__ fw2,
                                                 float* __restrict__ out)
{
    __shared__ float red[4][4][64];
    int tid = threadIdx.x;
    int dd = tid & 63;
    int d = blockIdx.x * 64 + dd;
    int jq = tid >> 6;
    float s[4] = {0.f, 0.f, 0.f, 0.f};
    const float* w = fw2 + (size_t)jq * 1024 * 1024 + d;
    const float* hm = Hm + jq * 1024;
    for (int j = 0; j < 1024; ++j) {
        float wv = w[(size_t)j * 1024];
        s[0] += hm[j] * wv;
        s[1] += hm[4096 + j] * wv;
        s[2] += hm[8192 + j] * wv;
        s[3] += hm[12288 + j] * wv;
    }
    #pragma unroll
    for (int bb = 0; bb < 4; ++bb) red[jq][bb][dd] = s[bb];
    __syncthreads();
    int b = jq;
    float tot = red[0][b][dd] + red[1][b][dd] + red[2][b][dd] + red[3][b][dd];
    out[(size_t)b * 1024 + d] = Mres[(size_t)b * 1024 + d] + tot;
}

extern "C" void kernel_launch(void* const* d_in, const int* in_sizes, int n_in,
                              void* d_out, int out_size, void* d_ws, size_t ws_size,
                              hipStream_t stream)
{
    const float* queries = (const float*)d_in[0];
    const int*   qlens   = (const int*)d_in[2];
    const int*   klens   = (const int*)d_in[3];
    const float* pe_q    = (const float*)d_in[4];
    const float* pe_k    = (const float*)d_in[5];
    const float* Wq      = (const float*)d_in[6];
    const float* Wk      = (const float*)d_in[7];
    const float* Wv      = (const float*)d_in[8];
    const float* fw1     = (const float*)d_in[9];
    const float* fw2     = (const float*)d_in[10];
    float* out = (float*)d_out;

    // arena (MB offsets), peak 78 MB
    char* w = (char*)d_ws;
    unsigned short* A3   = (unsigned short*)(w);                  // [0,30)  5120x3072 bf16
    unsigned short* B3   = (unsigned short*)(w + (30ll << 20));   // [30,42)
    float*          Qb   = (float*)(w + (42ll << 20));            // [42,58)
    float*          Kraw = (float*)(w + (58ll << 20));            // [58,74)
    float*          PEKW = (float*)(w + (74ll << 20));            // [74,78)
    // post-QK overlays (A3/B3 dead):
    float*          Vb   = (float*)(w);                           // [0,16)
    unsigned short* q16  = (unsigned short*)(w + (16ll << 20));   // [16,24)
    unsigned short* WvT  = (unsigned short*)(w + (24ll << 20));   // [24,26)
    unsigned short* fw1T = (unsigned short*)(w + (26ll << 20));   // [26,34)
    float*          Mres = (float*)(w + (34ll << 20));            // 16 KB
    float*          Hm   = (float*)(w + (35ll << 20));            // 64 KB
    unsigned short* h1   = (unsigned short*)(w + (42ll << 20));   // [42,74) over dead Qb/Kraw

    // 1) conversions feeding the stacked QK GEMM
    conv_a3 <<<4096, 256, 0, stream>>>(queries, pe_q, A3);
    conv_pe3<<<1024, 256, 0, stream>>>(pe_k, A3);
    conv_w3 <<<dim3(32, 32, 2), 256, 0, stream>>>(Wq, Wk, B3);
    // 2) stacked [Q|K|PEKW] GEMM: M=5120, N=2048, K=3072 (split-bf16)
    gemm_mfma<128,false><<<dim3(16, 40), 256, 0, stream>>>(
        A3, 3072, B3, 3072, 3072,
        nullptr, Qb, Kraw, PEKW, nullptr, 2048, 32);
    // 3) small conversions into dead A3/B3 space
    conv_q16<<<4096, 256, 0, stream>>>(queries, pe_q, q16);
    conv_wT <<<dim3(32, 32), 256, 0, stream>>>(Wv, WvT, 1024, 1024);
    conv_wT <<<dim3(128, 32), 256, 0, stream>>>(fw1, fw1T, 1024, 4096);
    // 4) V = (Kraw + PEKW) @ Wv   (f32 A folded+converted in staging)
    gemm_mfma<64,true><<<dim3(8, 64), 256, 0, stream>>>(
        Kraw, 1024, WvT, 1024, 1024,
        PEKW, Vb, nullptr, nullptr, nullptr, 1024, 8);
    // 5) attention (fp32 core, K=Kraw+PEKW) + residual -> res16 (in-place over q16)
    attn<<<dim3(16, 16, 4), 256, 0, stream>>>(Qb, Kraw, PEKW, Vb, q16, qlens, klens);
    // 6) FFN1: h1 = relu(res @ fw1)
    gemm_mfma<128,false><<<dim3(32, 32), 256, 0, stream>>>(
        q16, 1024, fw1T, 1024, 1024,
        nullptr, nullptr, nullptr, nullptr, h1, 4096, 1 | 16);
    // 7) means + final: out = mean_t(res) + mean_t(h1) @ fw2
    mean16<<<dim3(8, 4),  256, 0, stream>>>(q16, Mres, 1024);
    mean16<<<dim3(32, 4), 256, 0, stream>>>(h1, Hm, 4096);
    final_out<<<16, 256, 0, stream>>>(Mres, Hm, fw2, out);
}

// Round 5
// 542.973 us; speedup vs baseline: 1.0699x; 1.0699x over previous
//
#include <hip/hip_runtime.h>

#define T_ 1024
#define D_ 1024
#define B_ 4
#define H_ 16
#define DH_ 64
#define M_ (B_*T_)                 // 4096
#define NEG_ (-4294967295.0f)

typedef __attribute__((ext_vector_type(8))) short bf16x8;
typedef __attribute__((ext_vector_type(4))) float f32x4;

__device__ __forceinline__ float b2f(unsigned short u) {
    union { unsigned int i; float f; } v; v.i = ((unsigned int)u) << 16; return v.f;
}
__device__ __forceinline__ unsigned short f2b(float f) {
    unsigned int x = __float_as_uint(f);
    return (unsigned short)((x + 0x7fffu + ((x >> 16) & 1u)) >> 16);
}

typedef const unsigned int __attribute__((address_space(1)))* gas_p;
typedef unsigned int __attribute__((address_space(3)))* las_p;
__device__ __forceinline__ void gl_lds16(const void* g, void* l) {
    __builtin_amdgcn_global_load_lds((gas_p)g, (las_p)l, 16, 0, 0);
}

// ---------------- conv: A3 rows 0..4095 = [hi|lo|hi](q_in) ----------------
__global__ __launch_bounds__(256) void conv_a3(const float* __restrict__ q,
                                               const float* __restrict__ peq,
                                               unsigned short* __restrict__ A3)
{
    int i = blockIdx.x * 256 + threadIdx.x;
    int m = i >> 8, c4 = (i & 255) << 2;
    float4 qv = *(const float4*)(q + (size_t)m * D_ + c4);
    float4 p  = *(const float4*)(peq + (size_t)(m & (T_-1)) * D_ + c4);
    float x[4] = { qv.x + 32.f*p.x, qv.y + 32.f*p.y, qv.z + 32.f*p.z, qv.w + 32.f*p.w };
    ushort4 h, l;
    h.x = f2b(x[0]); h.y = f2b(x[1]); h.z = f2b(x[2]); h.w = f2b(x[3]);
    l.x = f2b(x[0] - b2f(h.x)); l.y = f2b(x[1] - b2f(h.y));
    l.z = f2b(x[2] - b2f(h.z)); l.w = f2b(x[3] - b2f(h.w));
    size_t base = (size_t)m * 3072;
    *(ushort4*)(A3 + base + c4) = h;
    *(ushort4*)(A3 + base + 1024 + c4) = l;
    *(ushort4*)(A3 + base + 2048 + c4) = h;
}

// ---------------- conv: A3 rows 4096..5119 = [hi|lo|hi](32*pe_k) ----------------
__global__ __launch_bounds__(256) void conv_pe3(const float* __restrict__ pek,
                                                unsigned short* __restrict__ A3)
{
    int i = blockIdx.x * 256 + threadIdx.x;
    int m = i >> 8, c4 = (i & 255) << 2;
    float4 p = *(const float4*)(pek + (size_t)m * D_ + c4);
    float x[4] = { 32.f*p.x, 32.f*p.y, 32.f*p.z, 32.f*p.w };
    ushort4 h, l;
    h.x = f2b(x[0]); h.y = f2b(x[1]); h.z = f2b(x[2]); h.w = f2b(x[3]);
    l.x = f2b(x[0] - b2f(h.x)); l.y = f2b(x[1] - b2f(h.y));
    l.z = f2b(x[2] - b2f(h.z)); l.w = f2b(x[3] - b2f(h.w));
    size_t base = (size_t)(m + 4096) * 3072;
    *(ushort4*)(A3 + base + c4) = h;
    *(ushort4*)(A3 + base + 1024 + c4) = l;
    *(ushort4*)(A3 + base + 2048 + c4) = h;
}

// ---------------- conv: q16 = hi(q_in) ----------------
__global__ __launch_bounds__(256) void conv_q16(const float* __restrict__ q,
                                                const float* __restrict__ peq,
                                                unsigned short* __restrict__ q16)
{
    int i = blockIdx.x * 256 + threadIdx.x;
    int m = i >> 8, c4 = (i & 255) << 2;
    float4 qv = *(const float4*)(q + (size_t)m * D_ + c4);
    float4 p  = *(const float4*)(peq + (size_t)(m & (T_-1)) * D_ + c4);
    ushort4 h;
    h.x = f2b(qv.x + 32.f*p.x); h.y = f2b(qv.y + 32.f*p.y);
    h.z = f2b(qv.z + 32.f*p.z); h.w = f2b(qv.w + 32.f*p.w);
    *(ushort4*)(q16 + (size_t)m * 1024 + c4) = h;
}

// ---------------- conv: k16 = bf16(Kraw + PEKW) ----------------
__global__ __launch_bounds__(256) void conv_k16(const float* __restrict__ Kraw,
                                                const float* __restrict__ pekw,
                                                unsigned short* __restrict__ k16)
{
    int i = blockIdx.x * 256 + threadIdx.x;
    int m = i >> 8, c4 = (i & 255) << 2;
    float4 kv = *(const float4*)(Kraw + (size_t)m * D_ + c4);
    float4 p  = *(const float4*)(pekw + (size_t)(m & (T_-1)) * D_ + c4);
    ushort4 h;
    h.x = f2b(kv.x + p.x); h.y = f2b(kv.y + p.y);
    h.z = f2b(kv.z + p.z); h.w = f2b(kv.w + p.w);
    *(ushort4*)(k16 + (size_t)m * 1024 + c4) = h;
}

// ---------------- conv: [Wq|Wk] -> B3 rows n in [0,2048), [hi|hi|lo], ld 3072 ----------------
__global__ __launch_bounds__(256) void conv_w3(const float* __restrict__ Wq,
                                               const float* __restrict__ Wk,
                                               unsigned short* __restrict__ B3)
{
    __shared__ float t[32][33];
    const float* W = blockIdx.z ? Wk : Wq;
    int k0 = blockIdx.y * 32, n0 = blockIdx.x * 32;
    int r = threadIdx.x >> 5, c = threadIdx.x & 31;
    #pragma unroll
    for (int rr = 0; rr < 4; ++rr)
        t[r + 8*rr][c] = W[(size_t)(k0 + r + 8*rr) * 1024 + n0 + c];
    __syncthreads();
    #pragma unroll
    for (int rr = 0; rr < 4; ++rr) {
        float v = t[c][r + 8*rr];
        unsigned short h = f2b(v);
        unsigned short l = f2b(v - b2f(h));
        size_t o = (size_t)(blockIdx.z * 1024 + n0 + r + 8*rr) * 3072 + k0 + c;
        B3[o] = h; B3[o + 1024] = h; B3[o + 2048] = l;
    }
}

// ---------------- conv: WT[n][k] = bf16(W[k][n]) ----------------
__global__ __launch_bounds__(256) void conv_wT(const float* __restrict__ W,
                                               unsigned short* __restrict__ WT,
                                               int K, int N)
{
    __shared__ float t[32][33];
    int k0 = blockIdx.y * 32, n0 = blockIdx.x * 32;
    int r = threadIdx.x >> 5, c = threadIdx.x & 31;
    #pragma unroll
    for (int rr = 0; rr < 4; ++rr)
        t[r + 8*rr][c] = W[(size_t)(k0 + r + 8*rr) * N + n0 + c];
    __syncthreads();
    #pragma unroll
    for (int rr = 0; rr < 4; ++rr)
        WT[(size_t)(n0 + r + 8*rr) * K + k0 + c] = f2b(t[c][r + 8*rr]);
}

// ---------------- counted-vmcnt pipelined bf16 MFMA GEMM ----------------
// C = A[M][lda] @ B_T[N][ldb]^T.  BM x 128 tile, BK=64, 4 waves, 2-deep prefetch.
// Loads for tile t+1/t+2 stay in flight across barriers (T4: never vmcnt(0) mid-loop).
// flags: 1 relu | 8 store-f32 | 16 store-bf16 | 32 stacked-QK epilogue
template<int BM>
__global__ __launch_bounds__(256) void gemm_mfma(
    const unsigned short* __restrict__ A, int lda,
    const unsigned short* __restrict__ B, int ldb, int K,
    float* __restrict__ outf, float* __restrict__ outf2, float* __restrict__ outp,
    unsigned short* __restrict__ outh, int N, int flags)
{
    constexpr int LOGBM = (BM == 128) ? 7 : 6;
    constexpr int WN = (BM == 128) ? 2 : 4;     // waves along n
    constexpr int FN = 8 / WN;                   // n-frags per wave
    constexpr int NA = BM / 32;                  // A chunks per thread
    __shared__ __align__(16) unsigned short As[2][BM * 64];
    __shared__ __align__(16) unsigned short Bs[2][128 * 64];
    const int tid = threadIdx.x;
    const int m0 = blockIdx.y * BM, n0 = blockIdx.x << 7;
    if ((flags & 32) && m0 >= 4096 && n0 < 1024) return;   // pe-rows x Q-cols: garbage
    const int lane = tid & 63, wave = tid >> 6;
    const int wm = (wave / WN) * 64;
    const int wn = (wave % WN) * (128 / WN);
    const int rl = lane & 15, kg = lane >> 4;

    int ca[NA]; const unsigned short* gA[NA];
    #pragma unroll
    for (int i = 0; i < NA; ++i) {
        int c = i * 256 + tid;
        ca[i] = c * 8;
        gA[i] = A + (size_t)(m0 + (c & (BM - 1))) * lda + (c >> LOGBM) * 8;
    }
    int cb[4]; const unsigned short* gB[4];
    #pragma unroll
    for (int i = 0; i < 4; ++i) {
        int c = i * 256 + tid;
        cb[i] = c * 8;
        gB[i] = B + (size_t)(n0 + (c & 127)) * ldb + (c >> 7) * 8;
    }

    f32x4 acc[4][FN];
    #pragma unroll
    for (int i = 0; i < 4; ++i)
        #pragma unroll
        for (int j = 0; j < FN; ++j) {
            acc[i][j][0] = 0.f; acc[i][j][1] = 0.f;
            acc[i][j][2] = 0.f; acc[i][j][3] = 0.f;
        }

    const int NT = K >> 6;
    // ---- prologue: stage tiles 0 and 1
    #pragma unroll
    for (int i = 0; i < 4; ++i)  gl_lds16(gB[i], &Bs[0][cb[i]]);
    #pragma unroll
    for (int i = 0; i < NA; ++i) gl_lds16(gA[i], &As[0][ca[i]]);
    #pragma unroll
    for (int i = 0; i < 4; ++i)  gl_lds16(gB[i] + 64, &Bs[1][cb[i]]);
    #pragma unroll
    for (int i = 0; i < NA; ++i) gl_lds16(gA[i] + 64, &As[1][ca[i]]);

    for (int t = 0; t < NT; ++t) {
        const int cur = t & 1;
        // wait for OWN tile-t loads only (tile t+1's 8/6 loads stay in flight)
        if (t + 1 < NT) {
            if constexpr (BM == 128) asm volatile("s_waitcnt vmcnt(8)" ::: "memory");
            else                     asm volatile("s_waitcnt vmcnt(6)" ::: "memory");
        } else {
            asm volatile("s_waitcnt vmcnt(0)" ::: "memory");
        }
        __builtin_amdgcn_s_barrier();
        __builtin_amdgcn_sched_barrier(0);
        // fragment loads from LDS
        bf16x8 av[2][4], bv[2][FN];
        #pragma unroll
        for (int tt = 0; tt < 2; ++tt) {
            #pragma unroll
            for (int f = 0; f < 4; ++f)
                av[tt][f] = *(const bf16x8*)&As[cur][(((tt*4 + kg) << LOGBM) + wm + (f << 4) + rl) * 8];
            #pragma unroll
            for (int f = 0; f < FN; ++f)
                bv[tt][f] = *(const bf16x8*)&Bs[cur][(((tt*4 + kg) << 7) + wn + (f << 4) + rl) * 8];
        }
        asm volatile("s_waitcnt lgkmcnt(0)" ::: "memory");
        __builtin_amdgcn_sched_barrier(0);
        __builtin_amdgcn_s_barrier();      // all waves have frags in regs; buf[cur] free
        __builtin_amdgcn_sched_barrier(0);
        // prefetch tile t+2 into buf[cur]
        if (t + 2 < NT) {
            const int ko = (t + 2) << 6;
            #pragma unroll
            for (int i = 0; i < 4; ++i)  gl_lds16(gB[i] + ko, &Bs[cur][cb[i]]);
            #pragma unroll
            for (int i = 0; i < NA; ++i) gl_lds16(gA[i] + ko, &As[cur][ca[i]]);
        }
        // MFMA
        #pragma unroll
        for (int fm = 0; fm < 4; ++fm)
            #pragma unroll
            for (int fn = 0; fn < FN; ++fn) {
                acc[fm][fn] = __builtin_amdgcn_mfma_f32_16x16x32_bf16(av[0][fm], bv[0][fn], acc[fm][fn], 0, 0, 0);
                acc[fm][fn] = __builtin_amdgcn_mfma_f32_16x16x32_bf16(av[1][fm], bv[1][fn], acc[fm][fn], 0, 0, 0);
            }
    }

    // ---- epilogue: C/D layout col=lane&15, row=(lane>>4)*4+reg
    #pragma unroll
    for (int fm = 0; fm < 4; ++fm) {
        int row = m0 + wm + (fm << 4) + (kg << 2);
        #pragma unroll
        for (int fn = 0; fn < FN; ++fn) {
            int col = n0 + wn + (fn << 4) + rl;
            #pragma unroll
            for (int r = 0; r < 4; ++r) {
                float x = acc[fm][fn][r];
                int rr = row + r;
                if (flags & 32) {
                    if (rr < 4096) {
                        if (col < 1024) outf[(size_t)rr * 1024 + col] = x;
                        else            outf2[(size_t)rr * 1024 + (col - 1024)] = x;
                    } else if (col >= 1024) {
                        outp[(size_t)(rr - 4096) * 1024 + (col - 1024)] = x;
                    }
                } else {
                    size_t idx = (size_t)rr * N + col;
                    if (flags & 1)  x = fmaxf(x, 0.f);
                    if (flags & 8)  outf[idx] = x;
                    if (flags & 16) outh[idx] = f2b(x);
                }
            }
        }
    }
}

// ---------------- flash-style fp32 attention; residual in bf16 in-place ----------------
__global__ __launch_bounds__(256) void attn(const float* __restrict__ Q,
                                            const float* __restrict__ Kraw,
                                            const float* __restrict__ pekw,
                                            const float* __restrict__ Vp,
                                            unsigned short* __restrict__ q16,
                                            const int* __restrict__ qlens,
                                            const int* __restrict__ klens)
{
    __shared__ __align__(16) float QsT[64][68];
    __shared__ __align__(16) float KP[64][68];
    __shared__ __align__(16) float Vs[64][68];
    __shared__ float rowm[64], rowl[64], rowfac[64];

    const int tid = threadIdx.x;
    const int qt = blockIdx.x, h = blockIdx.y, b = blockIdx.z;
    const int qbase = qt * 64;
    const int qlen = qlens[b], klen = klens[b];
    if (qbase >= qlen) return;

    {
        int r = tid >> 2;
        int cc = (tid & 3) * 16;
        const float* src = Q + ((size_t)(b * T_ + qbase + r)) * D_ + h * DH_ + cc;
        #pragma unroll
        for (int u = 0; u < 4; ++u) {
            float4 v = *(const float4*)(src + u * 4);
            QsT[cc + u*4 + 0][r] = v.x; QsT[cc + u*4 + 1][r] = v.y;
            QsT[cc + u*4 + 2][r] = v.z; QsT[cc + u*4 + 3][r] = v.w;
        }
    }
    if (tid < 64) { rowm[tid] = -3.0e38f; rowl[tid] = 0.f; }

    const int q0 = (tid >> 4) * 4;
    const int c0 = (tid & 15) * 4;
    float acc[4][4] = {};

    const int nt = (klen == 1) ? (T_/64) : ((klen + 63) >> 6);
    for (int kb = 0; kb < nt; ++kb) {
        const int kbase = kb * 64;
        __syncthreads();
        {
            int r = tid >> 2;
            int cc = (tid & 3) * 16;
            const float* ksrc = Kraw + ((size_t)(b * T_ + kbase + r)) * D_ + h * DH_ + cc;
            const float* psrc = pekw + (size_t)(kbase + r) * D_ + h * DH_ + cc;
            const float* vsrc = Vp + ((size_t)(b * T_ + kbase + r)) * D_ + h * DH_ + cc;
            #pragma unroll
            for (int u = 0; u < 4; ++u) {
                float4 v = *(const float4*)(ksrc + u * 4);
                float4 pv = *(const float4*)(psrc + u * 4);
                v.x += pv.x; v.y += pv.y; v.z += pv.z; v.w += pv.w;
                KP[cc + u*4 + 0][r] = v.x; KP[cc + u*4 + 1][r] = v.y;
                KP[cc + u*4 + 2][r] = v.z; KP[cc + u*4 + 3][r] = v.w;
                *(float4*)&Vs[r][cc + u*4] = *(const float4*)(vsrc + u * 4);
            }
        }
        __syncthreads();
        float s[4][4] = {};
        #pragma unroll 8
        for (int d = 0; d < 64; ++d) {
            float4 qa = *(float4*)&QsT[d][q0];
            float4 ka = *(float4*)&KP[d][c0];
            float qv[4] = {qa.x, qa.y, qa.z, qa.w};
            float kv[4] = {ka.x, ka.y, ka.z, ka.w};
            #pragma unroll
            for (int i = 0; i < 4; ++i)
                #pragma unroll
                for (int j = 0; j < 4; ++j) s[i][j] += qv[i] * kv[j];
        }
        __syncthreads();
        #pragma unroll
        for (int i = 0; i < 4; ++i) {
            int gq = qbase + q0 + i;
            #pragma unroll
            for (int j = 0; j < 4; ++j) {
                int gk = kbase + c0 + j;
                float v = s[i][j] * 0.125f;
                if (gk >= klen || gk == gq) v = NEG_;
                KP[c0 + j][q0 + i] = v;
            }
        }
        __syncthreads();
        {
            int q = tid >> 2, g = tid & 3;
            float mx = -3.0e38f;
            #pragma unroll
            for (int kk = 0; kk < 16; ++kk) mx = fmaxf(mx, KP[g * 16 + kk][q]);
            mx = fmaxf(mx, __shfl_xor(mx, 1));
            mx = fmaxf(mx, __shfl_xor(mx, 2));
            float mold = rowm[q];
            float mnew = fmaxf(mold, mx);
            float sum = 0.f;
            #pragma unroll
            for (int kk = 0; kk < 16; ++kk) {
                int k = g * 16 + kk;
                float p = __expf(KP[k][q] - mnew);
                KP[k][q] = p;
                sum += p;
            }
            sum += __shfl_xor(sum, 1);
            sum += __shfl_xor(sum, 2);
            float fac = __expf(mold - mnew);
            if (g == 0) { rowm[q] = mnew; rowl[q] = rowl[q] * fac + sum; rowfac[q] = fac; }
        }
        __syncthreads();
        {
            float f[4];
            #pragma unroll
            for (int i = 0; i < 4; ++i) f[i] = rowfac[q0 + i];
            #pragma unroll
            for (int i = 0; i < 4; ++i)
                #pragma unroll
                for (int j = 0; j < 4; ++j) acc[i][j] *= f[i];
            #pragma unroll 8
            for (int k = 0; k < 64; ++k) {
                float4 pa = *(float4*)&KP[k][q0];
                float4 vb = *(float4*)&Vs[k][c0];
                float pv[4] = {pa.x, pa.y, pa.z, pa.w};
                float vv[4] = {vb.x, vb.y, vb.z, vb.w};
                #pragma unroll
                for (int i = 0; i < 4; ++i)
                    #pragma unroll
                    for (int j = 0; j < 4; ++j) acc[i][j] += pv[i] * vv[j];
            }
        }
    }
    #pragma unroll
    for (int i = 0; i < 4; ++i) {
        int gq = qbase + q0 + i;
        float qm = (gq < qlen) ? 1.f : 0.f;
        float invl = qm / rowl[q0 + i];
        size_t off = ((size_t)(b * T_ + gq)) * D_ + h * DH_ + c0;
        ushort4 r4 = *(const ushort4*)(q16 + off);
        ushort4 o;
        o.x = f2b(acc[i][0] * invl + b2f(r4.x));
        o.y = f2b(acc[i][1] * invl + b2f(r4.y));
        o.z = f2b(acc[i][2] * invl + b2f(r4.z));
        o.w = f2b(acc[i][3] * invl + b2f(r4.w));
        *(ushort4*)(q16 + off) = o;
    }
}

// ---------------- mean over T of bf16 [4][1024][X] -> f32 [4][X] ----------------
__global__ __launch_bounds__(256) void mean16(const unsigned short* __restrict__ X,
                                              float* __restrict__ out, int Xdim)
{
    __shared__ float red[4][128];
    int tid = threadIdx.x;
    int b = blockIdx.y;
    int dbase = blockIdx.x * 128;
    int tq = tid >> 6, dd = tid & 63;
    int d = dbase + dd * 2;
    const unsigned short* p = X + ((size_t)b * T_ + tq * 256) * Xdim + d;
    float s0 = 0.f, s1 = 0.f;
    for (int t = 0; t < 256; ++t) {
        ushort2 v = *(const ushort2*)(p + (size_t)t * Xdim);
        s0 += b2f(v.x); s1 += b2f(v.y);
    }
    red[tq][dd*2] = s0; red[tq][dd*2 + 1] = s1;
    __syncthreads();
    if (tq == 0) {
        float a = red[0][dd*2] + red[1][dd*2] + red[2][dd*2] + red[3][dd*2];
        float c = red[0][dd*2+1] + red[1][dd*2+1] + red[2][dd*2+1] + red[3][dd*2+1];
        out[(size_t)b * Xdim + d]     = a * (1.f/1024.f);
        out[(size_t)b * Xdim + d + 1] = c * (1.f/1024.f);
    }
}

// ---------------- out[b][d] = Mres[b][d] + sum_j Hm[b][j]*fw2[j][d] ----------------
__global__ __launch_bounds__(256) void final_out(const float* __restrict__ Mres,
                                                 const float* __restrict__ Hm,
                                                 const float* __restrict__ fw2,
                                                 float* __restrict__ out)
{
    __shared__ float red[4][4][64];
    int tid = threadIdx.x;
    int dd = tid & 63;
    int d = blockIdx.x * 64 + dd;
    int jq = tid >> 6;
    float s[4] = {0.f, 0.f, 0.f, 0.f};
    const float* w = fw2 + (size_t)jq * 1024 * 1024 + d;
    const float* hm = Hm + jq * 1024;
    for (int j = 0; j < 1024; ++j) {
        float wv = w[(size_t)j * 1024];
        s[0] += hm[j] * wv;
        s[1] += hm[4096 + j] * wv;
        s[2] += hm[8192 + j] * wv;
        s[3] += hm[12288 + j] * wv;
    }
    #pragma unroll
    for (int bb = 0; bb < 4; ++bb) red[jq][bb][dd] = s[bb];
    __syncthreads();
    int b = jq;
    float tot = red[0][b][dd] + red[1][b][dd] + red[2][b][dd] + red[3][b][dd];
    out[(size_t)b * 1024 + d] = Mres[(size_t)b * 1024 + d] + tot;
}

extern "C" void kernel_launch(void* const* d_in, const int* in_sizes, int n_in,
                              void* d_out, int out_size, void* d_ws, size_t ws_size,
                              hipStream_t stream)
{
    const float* queries = (const float*)d_in[0];
    const int*   qlens   = (const int*)d_in[2];
    const int*   klens   = (const int*)d_in[3];
    const float* pe_q    = (const float*)d_in[4];
    const float* pe_k    = (const float*)d_in[5];
    const float* Wq      = (const float*)d_in[6];
    const float* Wk      = (const float*)d_in[7];
    const float* Wv      = (const float*)d_in[8];
    const float* fw1     = (const float*)d_in[9];
    const float* fw2     = (const float*)d_in[10];
    float* out = (float*)d_out;

    // arena (MB offsets), peak 78 MB
    char* w = (char*)d_ws;
    unsigned short* A3   = (unsigned short*)(w);                  // [0,30)  5120x3072 bf16
    unsigned short* B3   = (unsigned short*)(w + (30ll << 20));   // [30,42)
    float*          Qb   = (float*)(w + (42ll << 20));            // [42,58)
    float*          Kraw = (float*)(w + (58ll << 20));            // [58,74)
    float*          PEKW = (float*)(w + (74ll << 20));            // [74,78)
    // post-QK overlays (A3/B3 dead):
    float*          Vb   = (float*)(w);                           // [0,16)
    unsigned short* q16  = (unsigned short*)(w + (16ll << 20));   // [16,24)
    unsigned short* WvT  = (unsigned short*)(w + (24ll << 20));   // [24,26)
    unsigned short* fw1T = (unsigned short*)(w + (26ll << 20));   // [26,34)
    unsigned short* k16  = (unsigned short*)(w + (34ll << 20));   // [34,42)
    unsigned short* h1   = (unsigned short*)(w + (42ll << 20));   // [42,74) over dead Qb/Kraw
    float*          Mres = (float*)(w + (74ll << 20));            // 16 KB (over dead PEKW)
    float*          Hm   = (float*)(w + (75ll << 20));            // 64 KB

    // 1) conversions feeding the stacked QK GEMM
    conv_a3 <<<4096, 256, 0, stream>>>(queries, pe_q, A3);
    conv_pe3<<<1024, 256, 0, stream>>>(pe_k, A3);
    conv_w3 <<<dim3(32, 32, 2), 256, 0, stream>>>(Wq, Wk, B3);
    // 2) stacked [Q|K|PEKW] GEMM: M=5120, N=2048, K=3072 (split-bf16)
    gemm_mfma<128><<<dim3(16, 40), 256, 0, stream>>>(
        A3, 3072, B3, 3072, 3072,
        Qb, Kraw, PEKW, nullptr, 2048, 32);
    // 3) small conversions into dead A3/B3 space
    conv_q16<<<4096, 256, 0, stream>>>(queries, pe_q, q16);
    conv_wT <<<dim3(32, 32), 256, 0, stream>>>(Wv, WvT, 1024, 1024);
    conv_wT <<<dim3(128, 32), 256, 0, stream>>>(fw1, fw1T, 1024, 4096);
    conv_k16<<<4096, 256, 0, stream>>>(Kraw, PEKW, k16);
    // 4) V = k16 @ Wv
    gemm_mfma<64><<<dim3(8, 64), 256, 0, stream>>>(
        k16, 1024, WvT, 1024, 1024,
        Vb, nullptr, nullptr, nullptr, 1024, 8);
    // 5) attention (fp32 core, K=Kraw+PEKW) + residual -> res16 (in-place over q16)
    attn<<<dim3(16, 16, 4), 256, 0, stream>>>(Qb, Kraw, PEKW, Vb, q16, qlens, klens);
    // 6) FFN1: h1 = relu(res @ fw1)
    gemm_mfma<128><<<dim3(32, 32), 256, 0, stream>>>(
        q16, 1024, fw1T, 1024, 1024,
        nullptr, nullptr, nullptr, h1, 4096, 1 | 16);
    // 7) means + final: out = mean_t(res) + mean_t(h1) @ fw2
    mean16<<<dim3(8, 4),  256, 0, stream>>>(q16, Mres, 1024);
    mean16<<<dim3(32, 4), 256, 0, stream>>>(h1, Hm, 4096);
    final_out<<<16, 256, 0, stream>>>(Mres, Hm, fw2, out);
}

// Round 7
// 347.356 us; speedup vs baseline: 1.6724x; 1.5632x over previous
//
#include <hip/hip_runtime.h>

#define T_ 1024
#define D_ 1024
#define B_ 4
#define H_ 16
#define DH_ 64
#define M_ (B_*T_)                 // 4096
#define NEG_ (-4294967295.0f)

typedef __attribute__((ext_vector_type(8))) short bf16x8;
typedef __attribute__((ext_vector_type(4))) float f32x4;

__device__ __forceinline__ float b2f(unsigned short u) {
    union { unsigned int i; float f; } v; v.i = ((unsigned int)u) << 16; return v.f;
}
__device__ __forceinline__ unsigned short f2b(float f) {
    unsigned int x = __float_as_uint(f);
    return (unsigned short)((x + 0x7fffu + ((x >> 16) & 1u)) >> 16);
}

typedef const unsigned int __attribute__((address_space(1)))* gas_p;
typedef unsigned int __attribute__((address_space(3)))* las_p;
__device__ __forceinline__ void gl_lds16(const void* g, void* l) {
    __builtin_amdgcn_global_load_lds((gas_p)g, (las_p)l, 16, 0, 0);
}

// ---------------- conv: A3 rows 0..4095 = [hi|lo|hi](q_in) ----------------
__global__ __launch_bounds__(256) void conv_a3(const float* __restrict__ q,
                                               const float* __restrict__ peq,
                                               unsigned short* __restrict__ A3)
{
    int i = blockIdx.x * 256 + threadIdx.x;
    int m = i >> 8, c4 = (i & 255) << 2;
    float4 qv = *(const float4*)(q + (size_t)m * D_ + c4);
    float4 p  = *(const float4*)(peq + (size_t)(m & (T_-1)) * D_ + c4);
    float x[4] = { qv.x + 32.f*p.x, qv.y + 32.f*p.y, qv.z + 32.f*p.z, qv.w + 32.f*p.w };
    ushort4 h, l;
    h.x = f2b(x[0]); h.y = f2b(x[1]); h.z = f2b(x[2]); h.w = f2b(x[3]);
    l.x = f2b(x[0] - b2f(h.x)); l.y = f2b(x[1] - b2f(h.y));
    l.z = f2b(x[2] - b2f(h.z)); l.w = f2b(x[3] - b2f(h.w));
    size_t base = (size_t)m * 3072;
    *(ushort4*)(A3 + base + c4) = h;
    *(ushort4*)(A3 + base + 1024 + c4) = l;
    *(ushort4*)(A3 + base + 2048 + c4) = h;
}

// ---------------- conv: A3 rows 4096..5119 = [hi|lo|hi](32*pe_k) ----------------
__global__ __launch_bounds__(256) void conv_pe3(const float* __restrict__ pek,
                                                unsigned short* __restrict__ A3)
{
    int i = blockIdx.x * 256 + threadIdx.x;
    int m = i >> 8, c4 = (i & 255) << 2;
    float4 p = *(const float4*)(pek + (size_t)m * D_ + c4);
    float x[4] = { 32.f*p.x, 32.f*p.y, 32.f*p.z, 32.f*p.w };
    ushort4 h, l;
    h.x = f2b(x[0]); h.y = f2b(x[1]); h.z = f2b(x[2]); h.w = f2b(x[3]);
    l.x = f2b(x[0] - b2f(h.x)); l.y = f2b(x[1] - b2f(h.y));
    l.z = f2b(x[2] - b2f(h.z)); l.w = f2b(x[3] - b2f(h.w));
    size_t base = (size_t)(m + 4096) * 3072;
    *(ushort4*)(A3 + base + c4) = h;
    *(ushort4*)(A3 + base + 1024 + c4) = l;
    *(ushort4*)(A3 + base + 2048 + c4) = h;
}

// ---------------- conv: q16 = hi(q_in) ----------------
__global__ __launch_bounds__(256) void conv_q16(const float* __restrict__ q,
                                                const float* __restrict__ peq,
                                                unsigned short* __restrict__ q16)
{
    int i = blockIdx.x * 256 + threadIdx.x;
    int m = i >> 8, c4 = (i & 255) << 2;
    float4 qv = *(const float4*)(q + (size_t)m * D_ + c4);
    float4 p  = *(const float4*)(peq + (size_t)(m & (T_-1)) * D_ + c4);
    ushort4 h;
    h.x = f2b(qv.x + 32.f*p.x); h.y = f2b(qv.y + 32.f*p.y);
    h.z = f2b(qv.z + 32.f*p.z); h.w = f2b(qv.w + 32.f*p.w);
    *(ushort4*)(q16 + (size_t)m * 1024 + c4) = h;
}

// ---------------- conv: k16 = bf16(Kraw + PEKW) ----------------
__global__ __launch_bounds__(256) void conv_k16(const float* __restrict__ Kraw,
                                                const float* __restrict__ pekw,
                                                unsigned short* __restrict__ k16)
{
    int i = blockIdx.x * 256 + threadIdx.x;
    int m = i >> 8, c4 = (i & 255) << 2;
    float4 kv = *(const float4*)(Kraw + (size_t)m * D_ + c4);
    float4 p  = *(const float4*)(pekw + (size_t)(m & (T_-1)) * D_ + c4);
    ushort4 h;
    h.x = f2b(kv.x + p.x); h.y = f2b(kv.y + p.y);
    h.z = f2b(kv.z + p.z); h.w = f2b(kv.w + p.w);
    *(ushort4*)(k16 + (size_t)m * 1024 + c4) = h;
}

// ---------------- conv: [Wq|Wk] -> B3 rows n in [0,2048), [hi|hi|lo], ld 3072 ----------------
__global__ __launch_bounds__(256) void conv_w3(const float* __restrict__ Wq,
                                               const float* __restrict__ Wk,
                                               unsigned short* __restrict__ B3)
{
    __shared__ float t[32][33];
    const float* W = blockIdx.z ? Wk : Wq;
    int k0 = blockIdx.y * 32, n0 = blockIdx.x * 32;
    int r = threadIdx.x >> 5, c = threadIdx.x & 31;
    #pragma unroll
    for (int rr = 0; rr < 4; ++rr)
        t[r + 8*rr][c] = W[(size_t)(k0 + r + 8*rr) * 1024 + n0 + c];
    __syncthreads();
    #pragma unroll
    for (int rr = 0; rr < 4; ++rr) {
        float v = t[c][r + 8*rr];
        unsigned short h = f2b(v);
        unsigned short l = f2b(v - b2f(h));
        size_t o = (size_t)(blockIdx.z * 1024 + n0 + r + 8*rr) * 3072 + k0 + c;
        B3[o] = h; B3[o + 1024] = h; B3[o + 2048] = l;
    }
}

// ---------------- conv: WT[n][k] = bf16(W[k][n]) ----------------
__global__ __launch_bounds__(256) void conv_wT(const float* __restrict__ W,
                                               unsigned short* __restrict__ WT,
                                               int K, int N)
{
    __shared__ float t[32][33];
    int k0 = blockIdx.y * 32, n0 = blockIdx.x * 32;
    int r = threadIdx.x >> 5, c = threadIdx.x & 31;
    #pragma unroll
    for (int rr = 0; rr < 4; ++rr)
        t[r + 8*rr][c] = W[(size_t)(k0 + r + 8*rr) * N + n0 + c];
    __syncthreads();
    #pragma unroll
    for (int rr = 0; rr < 4; ++rr)
        WT[(size_t)(n0 + r + 8*rr) * K + k0 + c] = f2b(t[c][r + 8*rr]);
}

// ---------------- counted-vmcnt pipelined bf16 MFMA GEMM, coalesced+swizzled staging ----
// C = A[M][lda] @ B_T[N][ldb]^T.  BM x 128 tile, BK=64, 4 waves, 2-deep prefetch.
// LDS layout: row-major [BM][64] with chunk swizzle slot=row*8+(k8^(row&7));
// global source permuted per-lane so each 8-lane group reads one 128B row burst.
// flags: 1 relu | 8 store-f32 | 16 store-bf16 | 32 stacked-QK epilogue
template<int BM>
__global__ __launch_bounds__(256) void gemm_mfma(
    const unsigned short* __restrict__ A, int lda,
    const unsigned short* __restrict__ B, int ldb, int K,
    float* __restrict__ outf, float* __restrict__ outf2, float* __restrict__ outp,
    unsigned short* __restrict__ outh, int N, int flags)
{
    constexpr int WN = (BM == 128) ? 2 : 4;     // waves along n
    constexpr int FN = 8 / WN;                   // n-frags per wave
    constexpr int NA = BM / 32;                  // A chunks per thread
    __shared__ __align__(16) unsigned short As[2][BM * 64];
    __shared__ __align__(16) unsigned short Bs[2][128 * 64];
    const int tid = threadIdx.x;
    const int m0 = blockIdx.y * BM, n0 = blockIdx.x << 7;
    if ((flags & 32) && m0 >= 4096 && n0 < 1024) return;   // pe-rows x Q-cols: garbage
    const int lane = tid & 63, wave = tid >> 6;
    const int wm = (wave / WN) * 64;
    const int wn = (wave % WN) * (128 / WN);
    const int rl = lane & 15, kg = lane >> 4;
    const int rl7 = lane & 7;

    // staging: LDS slot c holds global chunk (row=c>>3, k8=(c&7)^(row&7))
    int ca[NA]; const unsigned short* gA[NA];
    #pragma unroll
    for (int i = 0; i < NA; ++i) {
        int c = i * 256 + tid;
        int row = c >> 3, k8 = (c & 7) ^ (row & 7);
        ca[i] = c * 8;
        gA[i] = A + (size_t)(m0 + row) * lda + k8 * 8;
    }
    int cb[4]; const unsigned short* gB[4];
    #pragma unroll
    for (int i = 0; i < 4; ++i) {
        int c = i * 256 + tid;
        int row = c >> 3, k8 = (c & 7) ^ (row & 7);
        cb[i] = c * 8;
        gB[i] = B + (size_t)(n0 + row) * ldb + k8 * 8;
    }

    // fragment LDS element offsets (swizzled read side)
    int aoff[2][4], boff[2][FN];
    #pragma unroll
    for (int tt = 0; tt < 2; ++tt) {
        #pragma unroll
        for (int f = 0; f < 4; ++f)
            aoff[tt][f] = (wm + (f << 4) + rl) * 64 + (((tt * 4 + kg) ^ rl7) << 3);
        #pragma unroll
        for (int f = 0; f < FN; ++f)
            boff[tt][f] = (wn + (f << 4) + rl) * 64 + (((tt * 4 + kg) ^ rl7) << 3);
    }

    f32x4 acc[4][FN];
    #pragma unroll
    for (int i = 0; i < 4; ++i)
        #pragma unroll
        for (int j = 0; j < FN; ++j) {
            acc[i][j][0] = 0.f; acc[i][j][1] = 0.f;
            acc[i][j][2] = 0.f; acc[i][j][3] = 0.f;
        }

    const int NT = K >> 6;
    // ---- prologue: stage tiles 0 and 1
    #pragma unroll
    for (int i = 0; i < 4; ++i)  gl_lds16(gB[i], &Bs[0][cb[i]]);
    #pragma unroll
    for (int i = 0; i < NA; ++i) gl_lds16(gA[i], &As[0][ca[i]]);
    #pragma unroll
    for (int i = 0; i < 4; ++i)  gl_lds16(gB[i] + 64, &Bs[1][cb[i]]);
    #pragma unroll
    for (int i = 0; i < NA; ++i) gl_lds16(gA[i] + 64, &As[1][ca[i]]);

    for (int t = 0; t < NT; ++t) {
        const int cur = t & 1;
        // wait for OWN tile-t loads only (tile t+1's loads stay in flight)
        if (t + 1 < NT) {
            if constexpr (BM == 128) asm volatile("s_waitcnt vmcnt(8)" ::: "memory");
            else                     asm volatile("s_waitcnt vmcnt(6)" ::: "memory");
        } else {
            asm volatile("s_waitcnt vmcnt(0)" ::: "memory");
        }
        __builtin_amdgcn_s_barrier();
        __builtin_amdgcn_sched_barrier(0);
        // fragment loads from LDS
        bf16x8 av[2][4], bv[2][FN];
        #pragma unroll
        for (int tt = 0; tt < 2; ++tt) {
            #pragma unroll
            for (int f = 0; f < 4; ++f)
                av[tt][f] = *(const bf16x8*)&As[cur][aoff[tt][f]];
            #pragma unroll
            for (int f = 0; f < FN; ++f)
                bv[tt][f] = *(const bf16x8*)&Bs[cur][boff[tt][f]];
        }
        asm volatile("s_waitcnt lgkmcnt(0)" ::: "memory");
        __builtin_amdgcn_sched_barrier(0);
        __builtin_amdgcn_s_barrier();      // all waves have frags in regs; buf[cur] free
        __builtin_amdgcn_sched_barrier(0);
        // prefetch tile t+2 into buf[cur]
        if (t + 2 < NT) {
            const int ko = (t + 2) << 6;
            #pragma unroll
            for (int i = 0; i < 4; ++i)  gl_lds16(gB[i] + ko, &Bs[cur][cb[i]]);
            #pragma unroll
            for (int i = 0; i < NA; ++i) gl_lds16(gA[i] + ko, &As[cur][ca[i]]);
        }
        // MFMA
        #pragma unroll
        for (int fm = 0; fm < 4; ++fm)
            #pragma unroll
            for (int fn = 0; fn < FN; ++fn) {
                acc[fm][fn] = __builtin_amdgcn_mfma_f32_16x16x32_bf16(av[0][fm], bv[0][fn], acc[fm][fn], 0, 0, 0);
                acc[fm][fn] = __builtin_amdgcn_mfma_f32_16x16x32_bf16(av[1][fm], bv[1][fn], acc[fm][fn], 0, 0, 0);
            }
    }

    // ---- epilogue: C/D layout col=lane&15, row=(lane>>4)*4+reg
    #pragma unroll
    for (int fm = 0; fm < 4; ++fm) {
        int row = m0 + wm + (fm << 4) + (kg << 2);
        #pragma unroll
        for (int fn = 0; fn < FN; ++fn) {
            int col = n0 + wn + (fn << 4) + rl;
            #pragma unroll
            for (int r = 0; r < 4; ++r) {
                float x = acc[fm][fn][r];
                int rr = row + r;
                if (flags & 32) {
                    if (rr < 4096) {
                        if (col < 1024) outf[(size_t)rr * 1024 + col] = x;
                        else            outf2[(size_t)rr * 1024 + (col - 1024)] = x;
                    } else if (col >= 1024) {
                        outp[(size_t)(rr - 4096) * 1024 + (col - 1024)] = x;
                    }
                } else {
                    size_t idx = (size_t)rr * N + col;
                    if (flags & 1)  x = fmaxf(x, 0.f);
                    if (flags & 8)  outf[idx] = x;
                    if (flags & 16) outh[idx] = f2b(x);
                }
            }
        }
    }
}

// ---------------- flash-style fp32 attention; residual in bf16 in-place ----------------
__global__ __launch_bounds__(256) void attn(const float* __restrict__ Q,
                                            const float* __restrict__ Kraw,
                                            const float* __restrict__ pekw,
                                            const float* __restrict__ Vp,
                                            unsigned short* __restrict__ q16,
                                            const int* __restrict__ qlens,
                                            const int* __restrict__ klens)
{
    __shared__ __align__(16) float QsT[64][68];
    __shared__ __align__(16) float KP[64][68];
    __shared__ __align__(16) float Vs[64][68];
    __shared__ float rowm[64], rowl[64], rowfac[64];

    const int tid = threadIdx.x;
    const int qt = blockIdx.x, h = blockIdx.y, b = blockIdx.z;
    const int qbase = qt * 64;
    const int qlen = qlens[b], klen = klens[b];
    if (qbase >= qlen) return;

    {
        int r = tid >> 2;
        int cc = (tid & 3) * 16;
        const float* src = Q + ((size_t)(b * T_ + qbase + r)) * D_ + h * DH_ + cc;
        #pragma unroll
        for (int u = 0; u < 4; ++u) {
            float4 v = *(const float4*)(src + u * 4);
            QsT[cc + u*4 + 0][r] = v.x; QsT[cc + u*4 + 1][r] = v.y;
            QsT[cc + u*4 + 2][r] = v.z; QsT[cc + u*4 + 3][r] = v.w;
        }
    }
    if (tid < 64) { rowm[tid] = -3.0e38f; rowl[tid] = 0.f; }

    const int q0 = (tid >> 4) * 4;
    const int c0 = (tid & 15) * 4;
    float acc[4][4] = {};

    const int nt = (klen == 1) ? (T_/64) : ((klen + 63) >> 6);
    for (int kb = 0; kb < nt; ++kb) {
        const int kbase = kb * 64;
        __syncthreads();
        {
            int r = tid >> 2;
            int cc = (tid & 3) * 16;
            const float* ksrc = Kraw + ((size_t)(b * T_ + kbase + r)) * D_ + h * DH_ + cc;
            const float* psrc = pekw + (size_t)(kbase + r) * D_ + h * DH_ + cc;
            const float* vsrc = Vp + ((size_t)(b * T_ + kbase + r)) * D_ + h * DH_ + cc;
            #pragma unroll
            for (int u = 0; u < 4; ++u) {
                float4 v = *(const float4*)(ksrc + u * 4);
                float4 pv = *(const float4*)(psrc + u * 4);
                v.x += pv.x; v.y += pv.y; v.z += pv.z; v.w += pv.w;
                KP[cc + u*4 + 0][r] = v.x; KP[cc + u*4 + 1][r] = v.y;
                KP[cc + u*4 + 2][r] = v.z; KP[cc + u*4 + 3][r] = v.w;
                *(float4*)&Vs[r][cc + u*4] = *(const float4*)(vsrc + u * 4);
            }
        }
        __syncthreads();
        float s[4][4] = {};
        #pragma unroll 8
        for (int d = 0; d < 64; ++d) {
            float4 qa = *(float4*)&QsT[d][q0];
            float4 ka = *(float4*)&KP[d][c0];
            float qv[4] = {qa.x, qa.y, qa.z, qa.w};
            float kv[4] = {ka.x, ka.y, ka.z, ka.w};
            #pragma unroll
            for (int i = 0; i < 4; ++i)
                #pragma unroll
                for (int j = 0; j < 4; ++j) s[i][j] += qv[i] * kv[j];
        }
        __syncthreads();
        #pragma unroll
        for (int i = 0; i < 4; ++i) {
            int gq = qbase + q0 + i;
            #pragma unroll
            for (int j = 0; j < 4; ++j) {
                int gk = kbase + c0 + j;
                float v = s[i][j] * 0.125f;
                if (gk >= klen || gk == gq) v = NEG_;
                KP[c0 + j][q0 + i] = v;
            }
        }
        __syncthreads();
        {
            int q = tid >> 2, g = tid & 3;
            float mx = -3.0e38f;
            #pragma unroll
            for (int kk = 0; kk < 16; ++kk) mx = fmaxf(mx, KP[g * 16 + kk][q]);
            mx = fmaxf(mx, __shfl_xor(mx, 1));
            mx = fmaxf(mx, __shfl_xor(mx, 2));
            float mold = rowm[q];
            float mnew = fmaxf(mold, mx);
            float sum = 0.f;
            #pragma unroll
            for (int kk = 0; kk < 16; ++kk) {
                int k = g * 16 + kk;
                float p = __expf(KP[k][q] - mnew);
                KP[k][q] = p;
                sum += p;
            }
            sum += __shfl_xor(sum, 1);
            sum += __shfl_xor(sum, 2);
            float fac = __expf(mold - mnew);
            if (g == 0) { rowm[q] = mnew; rowl[q] = rowl[q] * fac + sum; rowfac[q] = fac; }
        }
        __syncthreads();
        {
            float f[4];
            #pragma unroll
            for (int i = 0; i < 4; ++i) f[i] = rowfac[q0 + i];
            #pragma unroll
            for (int i = 0; i < 4; ++i)
                #pragma unroll
                for (int j = 0; j < 4; ++j) acc[i][j] *= f[i];
            #pragma unroll 8
            for (int k = 0; k < 64; ++k) {
                float4 pa = *(float4*)&KP[k][q0];
                float4 vb = *(float4*)&Vs[k][c0];
                float pv[4] = {pa.x, pa.y, pa.z, pa.w};
                float vv[4] = {vb.x, vb.y, vb.z, vb.w};
                #pragma unroll
                for (int i = 0; i < 4; ++i)
                    #pragma unroll
                    for (int j = 0; j < 4; ++j) acc[i][j] += pv[i] * vv[j];
            }
        }
    }
    #pragma unroll
    for (int i = 0; i < 4; ++i) {
        int gq = qbase + q0 + i;
        float qm = (gq < qlen) ? 1.f : 0.f;
        float invl = qm / rowl[q0 + i];
        size_t off = ((size_t)(b * T_ + gq)) * D_ + h * DH_ + c0;
        ushort4 r4 = *(const ushort4*)(q16 + off);
        ushort4 o;
        o.x = f2b(acc[i][0] * invl + b2f(r4.x));
        o.y = f2b(acc[i][1] * invl + b2f(r4.y));
        o.z = f2b(acc[i][2] * invl + b2f(r4.z));
        o.w = f2b(acc[i][3] * invl + b2f(r4.w));
        *(ushort4*)(q16 + off) = o;
    }
}

// ---------------- mean over T of bf16 [4][1024][X] -> f32 [4][X] ----------------
__global__ __launch_bounds__(256) void mean16(const unsigned short* __restrict__ X,
                                              float* __restrict__ out, int Xdim)
{
    __shared__ float red[4][128];
    int tid = threadIdx.x;
    int b = blockIdx.y;
    int dbase = blockIdx.x * 128;
    int tq = tid >> 6, dd = tid & 63;
    int d = dbase + dd * 2;
    const unsigned short* p = X + ((size_t)b * T_ + tq * 256) * Xdim + d;
    float s0 = 0.f, s1 = 0.f;
    for (int t = 0; t < 256; ++t) {
        ushort2 v = *(const ushort2*)(p + (size_t)t * Xdim);
        s0 += b2f(v.x); s1 += b2f(v.y);
    }
    red[tq][dd*2] = s0; red[tq][dd*2 + 1] = s1;
    __syncthreads();
    if (tq == 0) {
        float a = red[0][dd*2] + red[1][dd*2] + red[2][dd*2] + red[3][dd*2];
        float c = red[0][dd*2+1] + red[1][dd*2+1] + red[2][dd*2+1] + red[3][dd*2+1];
        out[(size_t)b * Xdim + d]     = a * (1.f/1024.f);
        out[(size_t)b * Xdim + d + 1] = c * (1.f/1024.f);
    }
}

// ---- partial: Pout[jy][b][d] = sum_{j in 128-chunk jy} Hm[b][j]*fw2[j][d], jy in [0,32) ----
__global__ __launch_bounds__(256) void final_partial(const float* __restrict__ Hm,
                                                     const float* __restrict__ fw2,
                                                     float* __restrict__ Pout)
{
    __shared__ float red[4][4][64];
    int tid = threadIdx.x;
    int dd = tid & 63;
    int d = blockIdx.x * 64 + dd;
    int jq = tid >> 6;                       // 4 sub-chunks of 32 rows
    int j0 = blockIdx.y * 128 + jq * 32;     // blockIdx.y in [0,32) -> j in [0,4096)
    float s[4] = {0.f, 0.f, 0.f, 0.f};
    for (int jj = 0; jj < 32; ++jj) {
        int j = j0 + jj;
        float wv = fw2[(size_t)j * 1024 + d];
        s[0] += Hm[j] * wv;
        s[1] += Hm[4096 + j] * wv;
        s[2] += Hm[8192 + j] * wv;
        s[3] += Hm[12288 + j] * wv;
    }
    #pragma unroll
    for (int bb = 0; bb < 4; ++bb) red[jq][bb][dd] = s[bb];
    __syncthreads();
    if (jq == 0) {
        #pragma unroll
        for (int bb = 0; bb < 4; ++bb) {
            float tot = red[0][bb][dd] + red[1][bb][dd] + red[2][bb][dd] + red[3][bb][dd];
            Pout[((size_t)blockIdx.y * 4 + bb) * 1024 + d] = tot;
        }
    }
}

// ---------------- out[b][d] = Mres[b][d] + sum_{jy<32} Pout[jy][b][d] ----------------
__global__ __launch_bounds__(256) void reduce_out(const float* __restrict__ Mres,
                                                  const float* __restrict__ Pout,
                                                  float* __restrict__ out)
{
    int idx = blockIdx.x * 256 + threadIdx.x;   // 4096 total
    int b = idx >> 10, d = idx & 1023;
    float s = Mres[(size_t)b * 1024 + d];
    #pragma unroll
    for (int jy = 0; jy < 32; ++jy)
        s += Pout[((size_t)jy * 4 + b) * 1024 + d];
    out[(size_t)b * 1024 + d] = s;
}

extern "C" void kernel_launch(void* const* d_in, const int* in_sizes, int n_in,
                              void* d_out, int out_size, void* d_ws, size_t ws_size,
                              hipStream_t stream)
{
    const float* queries = (const float*)d_in[0];
    const int*   qlens   = (const int*)d_in[2];
    const int*   klens   = (const int*)d_in[3];
    const float* pe_q    = (const float*)d_in[4];
    const float* pe_k    = (const float*)d_in[5];
    const float* Wq      = (const float*)d_in[6];
    const float* Wk      = (const float*)d_in[7];
    const float* Wv      = (const float*)d_in[8];
    const float* fw1     = (const float*)d_in[9];
    const float* fw2     = (const float*)d_in[10];
    float* out = (float*)d_out;

    // arena (MB offsets), peak 78 MB
    char* w = (char*)d_ws;
    unsigned short* A3   = (unsigned short*)(w);                  // [0,30)  5120x3072 bf16
    unsigned short* B3   = (unsigned short*)(w + (30ll << 20));   // [30,42)
    float*          Qb   = (float*)(w + (42ll << 20));            // [42,58)
    float*          Kraw = (float*)(w + (58ll << 20));            // [58,74)
    float*          PEKW = (float*)(w + (74ll << 20));            // [74,78)
    // post-QK overlays (A3/B3 dead):
    float*          Vb   = (float*)(w);                           // [0,16)
    unsigned short* q16  = (unsigned short*)(w + (16ll << 20));   // [16,24)
    unsigned short* WvT  = (unsigned short*)(w + (24ll << 20));   // [24,26)
    unsigned short* fw1T = (unsigned short*)(w + (26ll << 20));   // [26,34)
    unsigned short* k16  = (unsigned short*)(w + (34ll << 20));   // [34,42)
    unsigned short* h1   = (unsigned short*)(w + (42ll << 20));   // [42,74) over dead Qb/Kraw
    float*          Mres = (float*)(w + (74ll << 20));            // 16 KB (over dead PEKW)
    float*          Hm   = (float*)(w + (75ll << 20));            // 64 KB
    float*          Pout = (float*)(w + (76ll << 20));            // 512 KB

    // 1) conversions feeding the stacked QK GEMM
    conv_a3 <<<4096, 256, 0, stream>>>(queries, pe_q, A3);
    conv_pe3<<<1024, 256, 0, stream>>>(pe_k, A3);
    conv_w3 <<<dim3(32, 32, 2), 256, 0, stream>>>(Wq, Wk, B3);
    // 2) stacked [Q|K|PEKW] GEMM: M=5120, N=2048, K=3072 (split-bf16)
    gemm_mfma<128><<<dim3(16, 40), 256, 0, stream>>>(
        A3, 3072, B3, 3072, 3072,
        Qb, Kraw, PEKW, nullptr, 2048, 32);
    // 3) small conversions into dead A3/B3 space
    conv_q16<<<4096, 256, 0, stream>>>(queries, pe_q, q16);
    conv_wT <<<dim3(32, 32), 256, 0, stream>>>(Wv, WvT, 1024, 1024);
    conv_wT <<<dim3(128, 32), 256, 0, stream>>>(fw1, fw1T, 1024, 4096);
    conv_k16<<<4096, 256, 0, stream>>>(Kraw, PEKW, k16);
    // 4) V = k16 @ Wv
    gemm_mfma<64><<<dim3(8, 64), 256, 0, stream>>>(
        k16, 1024, WvT, 1024, 1024,
        Vb, nullptr, nullptr, nullptr, 1024, 8);
    // 5) attention (fp32 core, K=Kraw+PEKW) + residual -> res16 (in-place over q16)
    attn<<<dim3(16, 16, 4), 256, 0, stream>>>(Qb, Kraw, PEKW, Vb, q16, qlens, klens);
    // 6) FFN1: h1 = relu(res @ fw1)
    gemm_mfma<128><<<dim3(32, 32), 256, 0, stream>>>(
        q16, 1024, fw1T, 1024, 1024,
        nullptr, nullptr, nullptr, h1, 4096, 1 | 16);
    // 7) means + final: out = mean_t(res) + mean_t(h1) @ fw2
    mean16<<<dim3(8, 4),  256, 0, stream>>>(q16, Mres, 1024);
    mean16<<<dim3(32, 4), 256, 0, stream>>>(h1, Hm, 4096);
    final_partial<<<dim3(16, 32), 256, 0, stream>>>(Hm, fw2, Pout);
    reduce_out<<<16, 256, 0, stream>>>(Mres, Pout, out);
}

// Round 8
// 271.786 us; speedup vs baseline: 2.1374x; 1.2781x over previous
//
#include <hip/hip_runtime.h>

#define T_ 1024
#define D_ 1024
#define B_ 4
#define H_ 16
#define DH_ 64
#define M_ (B_*T_)                 // 4096
#define NEG_ (-4294967295.0f)

typedef __attribute__((ext_vector_type(8))) short bf16x8;
typedef __attribute__((ext_vector_type(4))) float f32x4;

__device__ __forceinline__ float b2f(unsigned short u) {
    union { unsigned int i; float f; } v; v.i = ((unsigned int)u) << 16; return v.f;
}
__device__ __forceinline__ unsigned short f2b(float f) {
    unsigned int x = __float_as_uint(f);
    return (unsigned short)((x + 0x7fffu + ((x >> 16) & 1u)) >> 16);
}

typedef const unsigned int __attribute__((address_space(1)))* gas_p;
typedef unsigned int __attribute__((address_space(3)))* las_p;
__device__ __forceinline__ void gl_lds16(const void* g, void* l) {
    __builtin_amdgcn_global_load_lds((gas_p)g, (las_p)l, 16, 0, 0);
}

// ---------------- conv: A3 rows 0..4095 = [hi|lo|hi](q_in) ----------------
__global__ __launch_bounds__(256) void conv_a3(const float* __restrict__ q,
                                               const float* __restrict__ peq,
                                               unsigned short* __restrict__ A3)
{
    int i = blockIdx.x * 256 + threadIdx.x;
    int m = i >> 8, c4 = (i & 255) << 2;
    float4 qv = *(const float4*)(q + (size_t)m * D_ + c4);
    float4 p  = *(const float4*)(peq + (size_t)(m & (T_-1)) * D_ + c4);
    float x[4] = { qv.x + 32.f*p.x, qv.y + 32.f*p.y, qv.z + 32.f*p.z, qv.w + 32.f*p.w };
    ushort4 h, l;
    h.x = f2b(x[0]); h.y = f2b(x[1]); h.z = f2b(x[2]); h.w = f2b(x[3]);
    l.x = f2b(x[0] - b2f(h.x)); l.y = f2b(x[1] - b2f(h.y));
    l.z = f2b(x[2] - b2f(h.z)); l.w = f2b(x[3] - b2f(h.w));
    size_t base = (size_t)m * 3072;
    *(ushort4*)(A3 + base + c4) = h;
    *(ushort4*)(A3 + base + 1024 + c4) = l;
    *(ushort4*)(A3 + base + 2048 + c4) = h;
}

// ---------------- conv: A3 rows 4096..5119 = [hi|lo|hi](32*pe_k) ----------------
__global__ __launch_bounds__(256) void conv_pe3(const float* __restrict__ pek,
                                                unsigned short* __restrict__ A3)
{
    int i = blockIdx.x * 256 + threadIdx.x;
    int m = i >> 8, c4 = (i & 255) << 2;
    float4 p = *(const float4*)(pek + (size_t)m * D_ + c4);
    float x[4] = { 32.f*p.x, 32.f*p.y, 32.f*p.z, 32.f*p.w };
    ushort4 h, l;
    h.x = f2b(x[0]); h.y = f2b(x[1]); h.z = f2b(x[2]); h.w = f2b(x[3]);
    l.x = f2b(x[0] - b2f(h.x)); l.y = f2b(x[1] - b2f(h.y));
    l.z = f2b(x[2] - b2f(h.z)); l.w = f2b(x[3] - b2f(h.w));
    size_t base = (size_t)(m + 4096) * 3072;
    *(ushort4*)(A3 + base + c4) = h;
    *(ushort4*)(A3 + base + 1024 + c4) = l;
    *(ushort4*)(A3 + base + 2048 + c4) = h;
}

// ---------------- conv: q16 = hi(q_in) ----------------
__global__ __launch_bounds__(256) void conv_q16(const float* __restrict__ q,
                                                const float* __restrict__ peq,
                                                unsigned short* __restrict__ q16)
{
    int i = blockIdx.x * 256 + threadIdx.x;
    int m = i >> 8, c4 = (i & 255) << 2;
    float4 qv = *(const float4*)(q + (size_t)m * D_ + c4);
    float4 p  = *(const float4*)(peq + (size_t)(m & (T_-1)) * D_ + c4);
    ushort4 h;
    h.x = f2b(qv.x + 32.f*p.x); h.y = f2b(qv.y + 32.f*p.y);
    h.z = f2b(qv.z + 32.f*p.z); h.w = f2b(qv.w + 32.f*p.w);
    *(ushort4*)(q16 + (size_t)m * 1024 + c4) = h;
}

// ---------------- conv: Khi/Klo = split_bf16(Kraw + PEKW) ----------------
__global__ __launch_bounds__(256) void conv_ksplit(const float* __restrict__ Kraw,
                                                   const float* __restrict__ pekw,
                                                   unsigned short* __restrict__ Hh,
                                                   unsigned short* __restrict__ Ll)
{
    int i = blockIdx.x * 256 + threadIdx.x;
    int m = i >> 8, c4 = (i & 255) << 2;
    float4 kv = *(const float4*)(Kraw + (size_t)m * D_ + c4);
    float4 p  = *(const float4*)(pekw + (size_t)(m & (T_-1)) * D_ + c4);
    float x[4] = { kv.x + p.x, kv.y + p.y, kv.z + p.z, kv.w + p.w };
    ushort4 h, l;
    h.x = f2b(x[0]); h.y = f2b(x[1]); h.z = f2b(x[2]); h.w = f2b(x[3]);
    l.x = f2b(x[0] - b2f(h.x)); l.y = f2b(x[1] - b2f(h.y));
    l.z = f2b(x[2] - b2f(h.z)); l.w = f2b(x[3] - b2f(h.w));
    *(ushort4*)(Hh + (size_t)m * 1024 + c4) = h;
    *(ushort4*)(Ll + (size_t)m * 1024 + c4) = l;
}

// ---------------- conv: [Wq|Wk] -> B3 rows n in [0,2048), [hi|hi|lo], ld 3072 ----------------
__global__ __launch_bounds__(256) void conv_w3(const float* __restrict__ Wq,
                                               const float* __restrict__ Wk,
                                               unsigned short* __restrict__ B3)
{
    __shared__ float t[32][33];
    const float* W = blockIdx.z ? Wk : Wq;
    int k0 = blockIdx.y * 32, n0 = blockIdx.x * 32;
    int r = threadIdx.x >> 5, c = threadIdx.x & 31;
    #pragma unroll
    for (int rr = 0; rr < 4; ++rr)
        t[r + 8*rr][c] = W[(size_t)(k0 + r + 8*rr) * 1024 + n0 + c];
    __syncthreads();
    #pragma unroll
    for (int rr = 0; rr < 4; ++rr) {
        float v = t[c][r + 8*rr];
        unsigned short h = f2b(v);
        unsigned short l = f2b(v - b2f(h));
        size_t o = (size_t)(blockIdx.z * 1024 + n0 + r + 8*rr) * 3072 + k0 + c;
        B3[o] = h; B3[o + 1024] = h; B3[o + 2048] = l;
    }
}

// ---------------- conv: WT[n][k] = bf16(W[k][n]) ----------------
__global__ __launch_bounds__(256) void conv_wT(const float* __restrict__ W,
                                               unsigned short* __restrict__ WT,
                                               int K, int N)
{
    __shared__ float t[32][33];
    int k0 = blockIdx.y * 32, n0 = blockIdx.x * 32;
    int r = threadIdx.x >> 5, c = threadIdx.x & 31;
    #pragma unroll
    for (int rr = 0; rr < 4; ++rr)
        t[r + 8*rr][c] = W[(size_t)(k0 + r + 8*rr) * N + n0 + c];
    __syncthreads();
    #pragma unroll
    for (int rr = 0; rr < 4; ++rr)
        WT[(size_t)(n0 + r + 8*rr) * K + k0 + c] = f2b(t[c][r + 8*rr]);
}

// ---------------- counted-vmcnt pipelined bf16 MFMA GEMM, coalesced+swizzled staging ----
// flags: 1 relu | 8 store-f32 | 16 store-bf16 | 32 stacked-QK epilogue | 64 V-transposed-bf16
template<int BM>
__global__ __launch_bounds__(256) void gemm_mfma(
    const unsigned short* __restrict__ A, int lda,
    const unsigned short* __restrict__ B, int ldb, int K,
    float* __restrict__ outf, float* __restrict__ outp,
    unsigned short* __restrict__ outh, unsigned short* __restrict__ outh2,
    int N, int flags)
{
    constexpr int WN = (BM == 128) ? 2 : 4;
    constexpr int FN = 8 / WN;
    constexpr int NA = BM / 32;
    __shared__ __align__(16) unsigned short As[2][BM * 64];
    __shared__ __align__(16) unsigned short Bs[2][128 * 64];
    const int tid = threadIdx.x;
    const int m0 = blockIdx.y * BM, n0 = blockIdx.x << 7;
    if ((flags & 32) && m0 >= 4096 && n0 < 1024) return;   // pe-rows x Q-cols: garbage
    const int lane = tid & 63, wave = tid >> 6;
    const int wm = (wave / WN) * 64;
    const int wn = (wave % WN) * (128 / WN);
    const int rl = lane & 15, kg = lane >> 4;
    const int rl7 = lane & 7;

    int ca[NA]; const unsigned short* gA[NA];
    #pragma unroll
    for (int i = 0; i < NA; ++i) {
        int c = i * 256 + tid;
        int row = c >> 3, k8 = (c & 7) ^ (row & 7);
        ca[i] = c * 8;
        gA[i] = A + (size_t)(m0 + row) * lda + k8 * 8;
    }
    int cb[4]; const unsigned short* gB[4];
    #pragma unroll
    for (int i = 0; i < 4; ++i) {
        int c = i * 256 + tid;
        int row = c >> 3, k8 = (c & 7) ^ (row & 7);
        cb[i] = c * 8;
        gB[i] = B + (size_t)(n0 + row) * ldb + k8 * 8;
    }

    int aoff[2][4], boff[2][FN];
    #pragma unroll
    for (int tt = 0; tt < 2; ++tt) {
        #pragma unroll
        for (int f = 0; f < 4; ++f)
            aoff[tt][f] = (wm + (f << 4) + rl) * 64 + (((tt * 4 + kg) ^ rl7) << 3);
        #pragma unroll
        for (int f = 0; f < FN; ++f)
            boff[tt][f] = (wn + (f << 4) + rl) * 64 + (((tt * 4 + kg) ^ rl7) << 3);
    }

    f32x4 acc[4][FN];
    #pragma unroll
    for (int i = 0; i < 4; ++i)
        #pragma unroll
        for (int j = 0; j < FN; ++j) {
            acc[i][j][0] = 0.f; acc[i][j][1] = 0.f;
            acc[i][j][2] = 0.f; acc[i][j][3] = 0.f;
        }

    const int NT = K >> 6;
    #pragma unroll
    for (int i = 0; i < 4; ++i)  gl_lds16(gB[i], &Bs[0][cb[i]]);
    #pragma unroll
    for (int i = 0; i < NA; ++i) gl_lds16(gA[i], &As[0][ca[i]]);
    #pragma unroll
    for (int i = 0; i < 4; ++i)  gl_lds16(gB[i] + 64, &Bs[1][cb[i]]);
    #pragma unroll
    for (int i = 0; i < NA; ++i) gl_lds16(gA[i] + 64, &As[1][ca[i]]);

    for (int t = 0; t < NT; ++t) {
        const int cur = t & 1;
        if (t + 1 < NT) {
            if constexpr (BM == 128) asm volatile("s_waitcnt vmcnt(8)" ::: "memory");
            else                     asm volatile("s_waitcnt vmcnt(6)" ::: "memory");
        } else {
            asm volatile("s_waitcnt vmcnt(0)" ::: "memory");
        }
        __builtin_amdgcn_s_barrier();
        __builtin_amdgcn_sched_barrier(0);
        bf16x8 av[2][4], bv[2][FN];
        #pragma unroll
        for (int tt = 0; tt < 2; ++tt) {
            #pragma unroll
            for (int f = 0; f < 4; ++f)
                av[tt][f] = *(const bf16x8*)&As[cur][aoff[tt][f]];
            #pragma unroll
            for (int f = 0; f < FN; ++f)
                bv[tt][f] = *(const bf16x8*)&Bs[cur][boff[tt][f]];
        }
        asm volatile("s_waitcnt lgkmcnt(0)" ::: "memory");
        __builtin_amdgcn_sched_barrier(0);
        __builtin_amdgcn_s_barrier();
        __builtin_amdgcn_sched_barrier(0);
        if (t + 2 < NT) {
            const int ko = (t + 2) << 6;
            #pragma unroll
            for (int i = 0; i < 4; ++i)  gl_lds16(gB[i] + ko, &Bs[cur][cb[i]]);
            #pragma unroll
            for (int i = 0; i < NA; ++i) gl_lds16(gA[i] + ko, &As[cur][ca[i]]);
        }
        #pragma unroll
        for (int fm = 0; fm < 4; ++fm)
            #pragma unroll
            for (int fn = 0; fn < FN; ++fn) {
                acc[fm][fn] = __builtin_amdgcn_mfma_f32_16x16x32_bf16(av[0][fm], bv[0][fn], acc[fm][fn], 0, 0, 0);
                acc[fm][fn] = __builtin_amdgcn_mfma_f32_16x16x32_bf16(av[1][fm], bv[1][fn], acc[fm][fn], 0, 0, 0);
            }
    }

    // epilogue: C/D layout col=lane&15, row=(lane>>4)*4+reg
    #pragma unroll
    for (int fm = 0; fm < 4; ++fm) {
        int row = m0 + wm + (fm << 4) + (kg << 2);
        #pragma unroll
        for (int fn = 0; fn < FN; ++fn) {
            int col = n0 + wn + (fn << 4) + rl;
            if (flags & 64) {
                // V: bf16 transposed store Vt[(b*16+h)*64 + dl][t], 4 consecutive t
                ushort4 u;
                u.x = f2b(acc[fm][fn][0]); u.y = f2b(acc[fm][fn][1]);
                u.z = f2b(acc[fm][fn][2]); u.w = f2b(acc[fm][fn][3]);
                size_t a = ((size_t)((row >> 10) * 16 + (col >> 6)) * 64 + (col & 63)) * 1024 + (row & 1023);
                *(ushort4*)(outh + a) = u;
                continue;
            }
            #pragma unroll
            for (int r = 0; r < 4; ++r) {
                float x = acc[fm][fn][r];
                int rr = row + r;
                if (flags & 32) {
                    if (rr < 4096) {
                        if (col < 1024) {
                            size_t idx = (size_t)rr * 1024 + col;
                            unsigned short hh = f2b(x);
                            outh[idx]  = hh;                    // Qhi
                            outh2[idx] = f2b(x - b2f(hh));      // Qlo
                        } else {
                            outf[(size_t)rr * 1024 + (col - 1024)] = x;   // Kraw
                        }
                    } else if (col >= 1024) {
                        outp[(size_t)(rr - 4096) * 1024 + (col - 1024)] = x;  // PEKW
                    }
                } else {
                    size_t idx = (size_t)rr * N + col;
                    if (flags & 1)  x = fmaxf(x, 0.f);
                    if (flags & 8)  outf[idx] = x;
                    if (flags & 16) outh[idx] = f2b(x);
                }
            }
        }
    }
}

// ---------------- MFMA flash attention (swapped QK, split-bf16 scores) ----------------
// grid: 1024 blocks, bh = blockIdx.x & 63 (fast -> XCD L2 locality), qt = blockIdx.x >> 6
// 4 waves x 16 q-rows each. K/V tiles of 64 keys staged swizzled; P via per-wave LDS.
__global__ __launch_bounds__(256) void attn_mfma(
    const unsigned short* __restrict__ Qhi, const unsigned short* __restrict__ Qlo,
    const unsigned short* __restrict__ Khi, const unsigned short* __restrict__ Klo,
    const unsigned short* __restrict__ Vt,
    unsigned short* __restrict__ q16,
    const int* __restrict__ qlens, const int* __restrict__ klens)
{
    __shared__ __align__(16) unsigned short KhiS[4096];
    __shared__ __align__(16) unsigned short KloS[4096];
    __shared__ __align__(16) unsigned short VtS[4096];
    __shared__ __align__(16) unsigned short Pl[4][1152];   // [16 q][72 k] per wave

    const int tid = threadIdx.x;
    const int bh = blockIdx.x & 63;
    const int qt = blockIdx.x >> 6;
    const int b = bh >> 4, h = bh & 15;
    const int qbase = qt * 64;
    const int qlen = qlens[b], klen = klens[b];
    if (qbase >= qlen) return;   // res16 already bf16(q_in)

    const int lane = tid & 63, wq = tid >> 6;
    const int rl = lane & 15, kg = lane >> 4, rl7 = lane & 7;
    const int gq = qbase + wq * 16 + rl;

    // Q B-fragments (col=q=lane&15, k=dh) held in registers for whole kernel
    bf16x8 qbh[2], qbl[2];
    {
        const unsigned short* p1 = Qhi + (size_t)(b * 1024 + gq) * 1024 + h * 64 + kg * 8;
        const unsigned short* p2 = Qlo + (size_t)(b * 1024 + gq) * 1024 + h * 64 + kg * 8;
        qbh[0] = *(const bf16x8*)p1;  qbh[1] = *(const bf16x8*)(p1 + 32);
        qbl[0] = *(const bf16x8*)p2;  qbl[1] = *(const bf16x8*)(p2 + 32);
    }

    // staging pointers (2 x 16B chunks per thread per buffer), swizzled source
    const unsigned short* gKh[2]; const unsigned short* gKl[2]; const unsigned short* gV[2];
    int cs[2];
    #pragma unroll
    for (int i = 0; i < 2; ++i) {
        int c = i * 256 + tid;
        int row = c >> 3, ch = (c & 7) ^ (row & 7);
        cs[i] = c * 8;
        gKh[i] = Khi + (size_t)(b * 1024 + row) * 1024 + h * 64 + ch * 8;
        gKl[i] = Klo + (size_t)(b * 1024 + row) * 1024 + h * 64 + ch * 8;
        gV[i]  = Vt + (size_t)(bh * 64 + row) * 1024 + ch * 8;
    }

    int akoff[4][2];   // A-frag offsets (rows=16*mf+rl, swizzled chunk)
    #pragma unroll
    for (int mf = 0; mf < 4; ++mf)
        #pragma unroll
        for (int kh = 0; kh < 2; ++kh)
            akoff[mf][kh] = (mf * 16 + rl) * 64 + (((kg + 4 * kh) ^ rl7) << 3);

    f32x4 o[4];
    #pragma unroll
    for (int i = 0; i < 4; ++i) { o[i][0]=0.f; o[i][1]=0.f; o[i][2]=0.f; o[i][3]=0.f; }
    float m_run = -3.0e38f, l_run = 0.f;
    const int nt = (klen == 1) ? (T_ / 64) : ((klen + 63) >> 6);

    for (int kb = 0; kb < nt; ++kb) {
        const int kbase = kb * 64;
        const size_t koff = (size_t)kbase * 1024;
        gl_lds16(gKh[0] + koff, &KhiS[cs[0]]);
        gl_lds16(gKh[1] + koff, &KhiS[cs[1]]);
        gl_lds16(gKl[0] + koff, &KloS[cs[0]]);
        gl_lds16(gKl[1] + koff, &KloS[cs[1]]);
        gl_lds16(gV[0] + kbase, &VtS[cs[0]]);
        gl_lds16(gV[1] + kbase, &VtS[cs[1]]);
        __syncthreads();

        // QK^T swapped: C[key][q], split-bf16 3-term
        float v[4][4];
        #pragma unroll
        for (int mf = 0; mf < 4; ++mf) {
            f32x4 s; s[0]=0.f; s[1]=0.f; s[2]=0.f; s[3]=0.f;
            #pragma unroll
            for (int kh = 0; kh < 2; ++kh) {
                bf16x8 ah = *(const bf16x8*)&KhiS[akoff[mf][kh]];
                bf16x8 al = *(const bf16x8*)&KloS[akoff[mf][kh]];
                s = __builtin_amdgcn_mfma_f32_16x16x32_bf16(ah, qbh[kh], s, 0, 0, 0);
                s = __builtin_amdgcn_mfma_f32_16x16x32_bf16(al, qbh[kh], s, 0, 0, 0);
                s = __builtin_amdgcn_mfma_f32_16x16x32_bf16(ah, qbl[kh], s, 0, 0, 0);
            }
            #pragma unroll
            for (int r = 0; r < 4; ++r) {
                int gk = kbase + mf * 16 + kg * 4 + r;
                float x = s[r] * 0.125f;
                if (gk >= klen || gk == gq) x = NEG_;
                v[mf][r] = x;
            }
        }
        // online softmax (per lane = one q-row; reduce across 4 lane-groups)
        float mt = -3.0e38f;
        #pragma unroll
        for (int mf = 0; mf < 4; ++mf)
            #pragma unroll
            for (int r = 0; r < 4; ++r) mt = fmaxf(mt, v[mf][r]);
        mt = fmaxf(mt, __shfl_xor(mt, 16));
        mt = fmaxf(mt, __shfl_xor(mt, 32));
        float mnew = fmaxf(m_run, mt);
        float fac = __expf(m_run - mnew);
        float sum = 0.f;
        #pragma unroll
        for (int mf = 0; mf < 4; ++mf) {
            ushort4 pb;
            float p0 = __expf(v[mf][0] - mnew); pb.x = f2b(p0);
            float p1 = __expf(v[mf][1] - mnew); pb.y = f2b(p1);
            float p2 = __expf(v[mf][2] - mnew); pb.z = f2b(p2);
            float p3 = __expf(v[mf][3] - mnew); pb.w = f2b(p3);
            sum += b2f(pb.x) + b2f(pb.y) + b2f(pb.z) + b2f(pb.w);
            *(ushort4*)&Pl[wq][rl * 72 + mf * 16 + kg * 4] = pb;
        }
        sum += __shfl_xor(sum, 16);
        sum += __shfl_xor(sum, 32);
        l_run = l_run * fac + sum;
        m_run = mnew;
        #pragma unroll
        for (int i = 0; i < 4; ++i) {
            o[i][0] *= fac; o[i][1] *= fac; o[i][2] *= fac; o[i][3] *= fac;
        }
        // PV: O^T[dh][q] += V^T-frag x P-frag (P re-laid via wave-private LDS)
        bf16x8 bp0 = *(const bf16x8*)&Pl[wq][rl * 72 + kg * 8];
        bf16x8 bp1 = *(const bf16x8*)&Pl[wq][rl * 72 + 32 + kg * 8];
        #pragma unroll
        for (int dmf = 0; dmf < 4; ++dmf) {
            bf16x8 a0 = *(const bf16x8*)&VtS[akoff[dmf][0]];
            bf16x8 a1 = *(const bf16x8*)&VtS[akoff[dmf][1]];
            o[dmf] = __builtin_amdgcn_mfma_f32_16x16x32_bf16(a0, bp0, o[dmf], 0, 0, 0);
            o[dmf] = __builtin_amdgcn_mfma_f32_16x16x32_bf16(a1, bp1, o[dmf], 0, 0, 0);
        }
        __syncthreads();
    }

    // epilogue: O^T lane holds col=q (fixed), rows dh = 16*dmf + 4*kg + r; RMW residual
    float invl = (gq < qlen) ? (1.f / l_run) : 0.f;
    #pragma unroll
    for (int dmf = 0; dmf < 4; ++dmf)
        #pragma unroll
        for (int r = 0; r < 4; ++r) {
            int dh = dmf * 16 + kg * 4 + r;
            size_t a = (size_t)(b * 1024 + gq) * 1024 + h * 64 + dh;
            float x = o[dmf][r] * invl + b2f(q16[a]);
            q16[a] = f2b(x);
        }
}

// ---------------- mean over T of bf16 [4][1024][X] -> f32 [4][X] ----------------
__global__ __launch_bounds__(256) void mean16(const unsigned short* __restrict__ X,
                                              float* __restrict__ out, int Xdim)
{
    __shared__ float red[4][128];
    int tid = threadIdx.x;
    int b = blockIdx.y;
    int dbase = blockIdx.x * 128;
    int tq = tid >> 6, dd = tid & 63;
    int d = dbase + dd * 2;
    const unsigned short* p = X + ((size_t)b * T_ + tq * 256) * Xdim + d;
    float s0 = 0.f, s1 = 0.f;
    for (int t = 0; t < 256; ++t) {
        ushort2 v = *(const ushort2*)(p + (size_t)t * Xdim);
        s0 += b2f(v.x); s1 += b2f(v.y);
    }
    red[tq][dd*2] = s0; red[tq][dd*2 + 1] = s1;
    __syncthreads();
    if (tq == 0) {
        float a = red[0][dd*2] + red[1][dd*2] + red[2][dd*2] + red[3][dd*2];
        float c = red[0][dd*2+1] + red[1][dd*2+1] + red[2][dd*2+1] + red[3][dd*2+1];
        out[(size_t)b * Xdim + d]     = a * (1.f/1024.f);
        out[(size_t)b * Xdim + d + 1] = c * (1.f/1024.f);
    }
}

// ---- partial: Pout[jy][b][d] = sum_{j in 128-chunk jy} Hm[b][j]*fw2[j][d], jy in [0,32) ----
__global__ __launch_bounds__(256) void final_partial(const float* __restrict__ Hm,
                                                     const float* __restrict__ fw2,
                                                     float* __restrict__ Pout)
{
    __shared__ float red[4][4][64];
    int tid = threadIdx.x;
    int dd = tid & 63;
    int d = blockIdx.x * 64 + dd;
    int jq = tid >> 6;
    int j0 = blockIdx.y * 128 + jq * 32;
    float s[4] = {0.f, 0.f, 0.f, 0.f};
    for (int jj = 0; jj < 32; ++jj) {
        int j = j0 + jj;
        float wv = fw2[(size_t)j * 1024 + d];
        s[0] += Hm[j] * wv;
        s[1] += Hm[4096 + j] * wv;
        s[2] += Hm[8192 + j] * wv;
        s[3] += Hm[12288 + j] * wv;
    }
    #pragma unroll
    for (int bb = 0; bb < 4; ++bb) red[jq][bb][dd] = s[bb];
    __syncthreads();
    if (jq == 0) {
        #pragma unroll
        for (int bb = 0; bb < 4; ++bb) {
            float tot = red[0][bb][dd] + red[1][bb][dd] + red[2][bb][dd] + red[3][bb][dd];
            Pout[((size_t)blockIdx.y * 4 + bb) * 1024 + d] = tot;
        }
    }
}

// ---------------- out[b][d] = Mres[b][d] + sum_{jy<32} Pout[jy][b][d] ----------------
__global__ __launch_bounds__(256) void reduce_out(const float* __restrict__ Mres,
                                                  const float* __restrict__ Pout,
                                                  float* __restrict__ out)
{
    int idx = blockIdx.x * 256 + threadIdx.x;
    int b = idx >> 10, d = idx & 1023;
    float s = Mres[(size_t)b * 1024 + d];
    #pragma unroll
    for (int jy = 0; jy < 32; ++jy)
        s += Pout[((size_t)jy * 4 + b) * 1024 + d];
    out[(size_t)b * 1024 + d] = s;
}

extern "C" void kernel_launch(void* const* d_in, const int* in_sizes, int n_in,
                              void* d_out, int out_size, void* d_ws, size_t ws_size,
                              hipStream_t stream)
{
    const float* queries = (const float*)d_in[0];
    const int*   qlens   = (const int*)d_in[2];
    const int*   klens   = (const int*)d_in[3];
    const float* pe_q    = (const float*)d_in[4];
    const float* pe_k    = (const float*)d_in[5];
    const float* Wq      = (const float*)d_in[6];
    const float* Wk      = (const float*)d_in[7];
    const float* Wv      = (const float*)d_in[8];
    const float* fw1     = (const float*)d_in[9];
    const float* fw2     = (const float*)d_in[10];
    float* out = (float*)d_out;

    // arena (MB offsets), peak 78 MB
    char* w = (char*)d_ws;
    unsigned short* A3    = (unsigned short*)(w);                  // [0,30)
    unsigned short* B3    = (unsigned short*)(w + (30ll << 20));   // [30,42)
    unsigned short* Qhi   = (unsigned short*)(w + (42ll << 20));   // [42,50)
    unsigned short* Qlo   = (unsigned short*)(w + (50ll << 20));   // [50,58)
    float*          Kraw  = (float*)(w + (58ll << 20));            // [58,74)
    float*          PEKW  = (float*)(w + (74ll << 20));            // [74,78)
    // post-QK overlays:
    unsigned short* Khi16 = (unsigned short*)(w);                  // [0,8)   over A3
    unsigned short* Klo16 = (unsigned short*)(w + (8ll  << 20));   // [8,16)
    unsigned short* q16   = (unsigned short*)(w + (16ll << 20));   // [16,24)
    unsigned short* WvT   = (unsigned short*)(w + (24ll << 20));   // [24,26)
    unsigned short* Vt    = (unsigned short*)(w + (30ll << 20));   // [30,38)  over B3
    unsigned short* fw1T  = (unsigned short*)(w + (58ll << 20));   // [58,66)  over Kraw (dead post-ksplit)
    unsigned short* h1    = (unsigned short*)(w + (26ll << 20));   // [26,58)  post-attn
    float*          Mres  = (float*)(w + (74ll << 20));            // over dead PEKW
    float*          Hm    = (float*)(w + (75ll << 20));
    float*          Pout  = (float*)(w + (76ll << 20));

    // 1) conversions feeding the stacked QK GEMM
    conv_a3 <<<4096, 256, 0, stream>>>(queries, pe_q, A3);
    conv_pe3<<<1024, 256, 0, stream>>>(pe_k, A3);
    conv_w3 <<<dim3(32, 32, 2), 256, 0, stream>>>(Wq, Wk, B3);
    // 2) stacked [Q|K|PEKW] GEMM: M=5120, N=2048, K=3072; Q emitted as split-bf16
    gemm_mfma<128><<<dim3(16, 40), 256, 0, stream>>>(
        A3, 3072, B3, 3072, 3072,
        Kraw, PEKW, Qhi, Qlo, 2048, 32);
    // 3) K split + residual base + weight preps
    conv_ksplit<<<4096, 256, 0, stream>>>(Kraw, PEKW, Khi16, Klo16);
    conv_q16<<<4096, 256, 0, stream>>>(queries, pe_q, q16);
    conv_wT <<<dim3(32, 32), 256, 0, stream>>>(Wv, WvT, 1024, 1024);
    conv_wT <<<dim3(128, 32), 256, 0, stream>>>(fw1, fw1T, 1024, 4096);
    // 4) V = Khi16 @ Wv, stored bf16 transposed: Vt[b,h][dh][t]
    gemm_mfma<64><<<dim3(8, 64), 256, 0, stream>>>(
        Khi16, 1024, WvT, 1024, 1024,
        nullptr, nullptr, Vt, nullptr, 1024, 64);
    // 5) MFMA attention + residual -> res16 (in-place over q16)
    attn_mfma<<<1024, 256, 0, stream>>>(Qhi, Qlo, Khi16, Klo16, Vt, q16, qlens, klens);
    // 6) FFN1: h1 = relu(res @ fw1)
    gemm_mfma<128><<<dim3(32, 32), 256, 0, stream>>>(
        q16, 1024, fw1T, 1024, 1024,
        nullptr, nullptr, h1, nullptr, 4096, 1 | 16);
    // 7) means + final: out = mean_t(res) + mean_t(h1) @ fw2
    mean16<<<dim3(8, 4),  256, 0, stream>>>(q16, Mres, 1024);
    mean16<<<dim3(32, 4), 256, 0, stream>>>(h1, Hm, 4096);
    final_partial<<<dim3(16, 32), 256, 0, stream>>>(Hm, fw2, Pout);
    reduce_out<<<16, 256, 0, stream>>>(Mres, Pout, out);
}

// Round 9
// 205.028 us; speedup vs baseline: 2.8334x; 1.3256x over previous
//
#include <hip/hip_runtime.h>

#define T_ 1024
#define D_ 1024
#define B_ 4
#define H_ 16
#define DH_ 64
#define M_ (B_*T_)                 // 4096
#define NEG_ (-4294967295.0f)

typedef __attribute__((ext_vector_type(8))) _Float16 f16x8;
typedef __attribute__((ext_vector_type(4))) float f32x4;

__device__ __forceinline__ unsigned short f2h(float f) {
    _Float16 h = (_Float16)f; unsigned short u; __builtin_memcpy(&u, &h, 2); return u;
}
__device__ __forceinline__ float h2f(unsigned short u) {
    _Float16 h; __builtin_memcpy(&h, &u, 2); return (float)h;
}

typedef const unsigned int __attribute__((address_space(1)))* gas_p;
typedef unsigned int __attribute__((address_space(3)))* las_p;
__device__ __forceinline__ void gl_lds16(const void* g, void* l) {
    __builtin_amdgcn_global_load_lds((gas_p)g, (las_p)l, 16, 0, 0);
}

// ---------------- conv: A2 rows 0..4095 = fp16(q_in)  (this region doubles as q16) ----
__global__ __launch_bounds__(256) void conv_af16(const float* __restrict__ q,
                                                 const float* __restrict__ peq,
                                                 unsigned short* __restrict__ A2)
{
    int i = blockIdx.x * 256 + threadIdx.x;
    int m = i >> 8, c4 = (i & 255) << 2;
    float4 qv = *(const float4*)(q + (size_t)m * D_ + c4);
    float4 p  = *(const float4*)(peq + (size_t)(m & (T_-1)) * D_ + c4);
    ushort4 h;
    h.x = f2h(qv.x + 32.f*p.x); h.y = f2h(qv.y + 32.f*p.y);
    h.z = f2h(qv.z + 32.f*p.z); h.w = f2h(qv.w + 32.f*p.w);
    *(ushort4*)(A2 + (size_t)m * 1024 + c4) = h;
}

// ---------------- conv: A2 rows 4096..5119 = fp16(32*pe_k) ----------------
__global__ __launch_bounds__(256) void conv_pef16(const float* __restrict__ pek,
                                                  unsigned short* __restrict__ A2)
{
    int i = blockIdx.x * 256 + threadIdx.x;
    int m = i >> 8, c4 = (i & 255) << 2;
    float4 p = *(const float4*)(pek + (size_t)m * D_ + c4);
    ushort4 h;
    h.x = f2h(32.f*p.x); h.y = f2h(32.f*p.y);
    h.z = f2h(32.f*p.z); h.w = f2h(32.f*p.w);
    *(ushort4*)(A2 + (size_t)(m + 4096) * 1024 + c4) = h;
}

// ---------------- conv: [Wq|Wk] -> B2[n][k] fp16, n in [0,2048) ----------------
__global__ __launch_bounds__(256) void conv_w2(const float* __restrict__ Wq,
                                               const float* __restrict__ Wk,
                                               unsigned short* __restrict__ B2)
{
    __shared__ float t[32][33];
    const float* W = blockIdx.z ? Wk : Wq;
    int k0 = blockIdx.y * 32, n0 = blockIdx.x * 32;
    int r = threadIdx.x >> 5, c = threadIdx.x & 31;
    #pragma unroll
    for (int rr = 0; rr < 4; ++rr)
        t[r + 8*rr][c] = W[(size_t)(k0 + r + 8*rr) * 1024 + n0 + c];
    __syncthreads();
    #pragma unroll
    for (int rr = 0; rr < 4; ++rr)
        B2[(size_t)(blockIdx.z * 1024 + n0 + r + 8*rr) * 1024 + k0 + c] = f2h(t[c][r + 8*rr]);
}

// ---------------- conv: WT[n][k] = fp16(W[k][n]) ----------------
__global__ __launch_bounds__(256) void conv_wT(const float* __restrict__ W,
                                               unsigned short* __restrict__ WT,
                                               int K, int N)
{
    __shared__ float t[32][33];
    int k0 = blockIdx.y * 32, n0 = blockIdx.x * 32;
    int r = threadIdx.x >> 5, c = threadIdx.x & 31;
    #pragma unroll
    for (int rr = 0; rr < 4; ++rr)
        t[r + 8*rr][c] = W[(size_t)(k0 + r + 8*rr) * N + n0 + c];
    __syncthreads();
    #pragma unroll
    for (int rr = 0; rr < 4; ++rr)
        WT[(size_t)(n0 + r + 8*rr) * K + k0 + c] = f2h(t[c][r + 8*rr]);
}

// ---------------- conv: Kh16 = fp16(Kraw + PEKW) ----------------
__global__ __launch_bounds__(256) void conv_kh(const float* __restrict__ Kraw,
                                               const float* __restrict__ pekw,
                                               unsigned short* __restrict__ Kh16)
{
    int i = blockIdx.x * 256 + threadIdx.x;
    int m = i >> 8, c4 = (i & 255) << 2;
    float4 kv = *(const float4*)(Kraw + (size_t)m * D_ + c4);
    float4 p  = *(const float4*)(pekw + (size_t)(m & (T_-1)) * D_ + c4);
    ushort4 h;
    h.x = f2h(kv.x + p.x); h.y = f2h(kv.y + p.y);
    h.z = f2h(kv.z + p.z); h.w = f2h(kv.w + p.w);
    *(ushort4*)(Kh16 + (size_t)m * 1024 + c4) = h;
}

// ---------------- counted-vmcnt pipelined fp16 MFMA GEMM, coalesced+swizzled staging ----
// flags: 1 relu | 8 store-f32 | 16 store-fp16 | 32 stacked-QK epilogue | 64 V-transposed-fp16
template<int BM>
__global__ __launch_bounds__(256) void gemm_mfma(
    const unsigned short* __restrict__ A, int lda,
    const unsigned short* __restrict__ B, int ldb, int K,
    float* __restrict__ outf, float* __restrict__ outp,
    unsigned short* __restrict__ outh, int N, int flags)
{
    constexpr int WN = (BM == 128) ? 2 : 4;
    constexpr int FN = 8 / WN;
    constexpr int NA = BM / 32;
    __shared__ __align__(16) unsigned short As[2][BM * 64];
    __shared__ __align__(16) unsigned short Bs[2][128 * 64];
    const int tid = threadIdx.x;
    const int m0 = blockIdx.y * BM, n0 = blockIdx.x << 7;
    if ((flags & 32) && m0 >= 4096 && n0 < 1024) return;   // pe-rows x Q-cols: garbage
    const int lane = tid & 63, wave = tid >> 6;
    const int wm = (wave / WN) * 64;
    const int wn = (wave % WN) * (128 / WN);
    const int rl = lane & 15, kg = lane >> 4;
    const int rl7 = lane & 7;

    int ca[NA]; const unsigned short* gA[NA];
    #pragma unroll
    for (int i = 0; i < NA; ++i) {
        int c = i * 256 + tid;
        int row = c >> 3, k8 = (c & 7) ^ (row & 7);
        ca[i] = c * 8;
        gA[i] = A + (size_t)(m0 + row) * lda + k8 * 8;
    }
    int cb[4]; const unsigned short* gB[4];
    #pragma unroll
    for (int i = 0; i < 4; ++i) {
        int c = i * 256 + tid;
        int row = c >> 3, k8 = (c & 7) ^ (row & 7);
        cb[i] = c * 8;
        gB[i] = B + (size_t)(n0 + row) * ldb + k8 * 8;
    }

    int aoff[2][4], boff[2][FN];
    #pragma unroll
    for (int tt = 0; tt < 2; ++tt) {
        #pragma unroll
        for (int f = 0; f < 4; ++f)
            aoff[tt][f] = (wm + (f << 4) + rl) * 64 + (((tt * 4 + kg) ^ rl7) << 3);
        #pragma unroll
        for (int f = 0; f < FN; ++f)
            boff[tt][f] = (wn + (f << 4) + rl) * 64 + (((tt * 4 + kg) ^ rl7) << 3);
    }

    f32x4 acc[4][FN];
    #pragma unroll
    for (int i = 0; i < 4; ++i)
        #pragma unroll
        for (int j = 0; j < FN; ++j) {
            acc[i][j][0] = 0.f; acc[i][j][1] = 0.f;
            acc[i][j][2] = 0.f; acc[i][j][3] = 0.f;
        }

    const int NT = K >> 6;
    #pragma unroll
    for (int i = 0; i < 4; ++i)  gl_lds16(gB[i], &Bs[0][cb[i]]);
    #pragma unroll
    for (int i = 0; i < NA; ++i) gl_lds16(gA[i], &As[0][ca[i]]);
    #pragma unroll
    for (int i = 0; i < 4; ++i)  gl_lds16(gB[i] + 64, &Bs[1][cb[i]]);
    #pragma unroll
    for (int i = 0; i < NA; ++i) gl_lds16(gA[i] + 64, &As[1][ca[i]]);

    for (int t = 0; t < NT; ++t) {
        const int cur = t & 1;
        if (t + 1 < NT) {
            if constexpr (BM == 128) asm volatile("s_waitcnt vmcnt(8)" ::: "memory");
            else                     asm volatile("s_waitcnt vmcnt(6)" ::: "memory");
        } else {
            asm volatile("s_waitcnt vmcnt(0)" ::: "memory");
        }
        __builtin_amdgcn_s_barrier();
        __builtin_amdgcn_sched_barrier(0);
        f16x8 av[2][4], bv[2][FN];
        #pragma unroll
        for (int tt = 0; tt < 2; ++tt) {
            #pragma unroll
            for (int f = 0; f < 4; ++f)
                av[tt][f] = *(const f16x8*)&As[cur][aoff[tt][f]];
            #pragma unroll
            for (int f = 0; f < FN; ++f)
                bv[tt][f] = *(const f16x8*)&Bs[cur][boff[tt][f]];
        }
        asm volatile("s_waitcnt lgkmcnt(0)" ::: "memory");
        __builtin_amdgcn_sched_barrier(0);
        __builtin_amdgcn_s_barrier();
        __builtin_amdgcn_sched_barrier(0);
        if (t + 2 < NT) {
            const int ko = (t + 2) << 6;
            #pragma unroll
            for (int i = 0; i < 4; ++i)  gl_lds16(gB[i] + ko, &Bs[cur][cb[i]]);
            #pragma unroll
            for (int i = 0; i < NA; ++i) gl_lds16(gA[i] + ko, &As[cur][ca[i]]);
        }
        #pragma unroll
        for (int fm = 0; fm < 4; ++fm)
            #pragma unroll
            for (int fn = 0; fn < FN; ++fn) {
                acc[fm][fn] = __builtin_amdgcn_mfma_f32_16x16x32_f16(av[0][fm], bv[0][fn], acc[fm][fn], 0, 0, 0);
                acc[fm][fn] = __builtin_amdgcn_mfma_f32_16x16x32_f16(av[1][fm], bv[1][fn], acc[fm][fn], 0, 0, 0);
            }
    }

    // epilogue: C/D layout col=lane&15, row=(lane>>4)*4+reg
    #pragma unroll
    for (int fm = 0; fm < 4; ++fm) {
        int row = m0 + wm + (fm << 4) + (kg << 2);
        #pragma unroll
        for (int fn = 0; fn < FN; ++fn) {
            int col = n0 + wn + (fn << 4) + rl;
            if (flags & 64) {
                // V: fp16 transposed store Vt[(b*16+h)*64 + dh][t], 4 consecutive t
                ushort4 u;
                u.x = f2h(acc[fm][fn][0]); u.y = f2h(acc[fm][fn][1]);
                u.z = f2h(acc[fm][fn][2]); u.w = f2h(acc[fm][fn][3]);
                size_t a = ((size_t)((row >> 10) * 16 + (col >> 6)) * 64 + (col & 63)) * 1024 + (row & 1023);
                *(ushort4*)(outh + a) = u;
                continue;
            }
            #pragma unroll
            for (int r = 0; r < 4; ++r) {
                float x = acc[fm][fn][r];
                int rr = row + r;
                if (flags & 32) {
                    if (rr < 4096) {
                        if (col < 1024) outh[(size_t)rr * 1024 + col] = f2h(x);          // Q fp16
                        else            outf[(size_t)rr * 1024 + (col - 1024)] = x;      // Kraw f32
                    } else if (col >= 1024) {
                        outp[(size_t)(rr - 4096) * 1024 + (col - 1024)] = x;             // PEKW
                    }
                } else {
                    size_t idx = (size_t)rr * N + col;
                    if (flags & 1)  x = fmaxf(x, 0.f);
                    if (flags & 8)  outf[idx] = x;
                    if (flags & 16) outh[idx] = f2h(x);
                }
            }
        }
    }
}

// ---------------- MFMA flash attention (swapped QK, fp16) ----------------
// grid: 1024 blocks, bh = blockIdx.x & 63 (fast -> XCD L2 locality), qt = blockIdx.x >> 6
__global__ __launch_bounds__(256) void attn_mfma(
    const unsigned short* __restrict__ Qh,
    const unsigned short* __restrict__ Kh,
    const unsigned short* __restrict__ Vt,
    unsigned short* __restrict__ q16,
    const int* __restrict__ qlens, const int* __restrict__ klens)
{
    __shared__ __align__(16) unsigned short KS[4096];
    __shared__ __align__(16) unsigned short VtS[4096];
    __shared__ __align__(16) unsigned short Pl[4][1152];   // [16 q][72 k] per wave

    const int tid = threadIdx.x;
    const int bh = blockIdx.x & 63;
    const int qt = blockIdx.x >> 6;
    const int b = bh >> 4, h = bh & 15;
    const int qbase = qt * 64;
    const int qlen = qlens[b], klen = klens[b];
    if (qbase >= qlen) return;   // q16 already fp16(q_in)

    const int lane = tid & 63, wq = tid >> 6;
    const int rl = lane & 15, kg = lane >> 4, rl7 = lane & 7;
    const int gq = qbase + wq * 16 + rl;

    // Q B-fragments (col=q=lane&15, k=dh)
    f16x8 qb[2];
    {
        const unsigned short* p1 = Qh + (size_t)(b * 1024 + gq) * 1024 + h * 64 + kg * 8;
        qb[0] = *(const f16x8*)p1;  qb[1] = *(const f16x8*)(p1 + 32);
    }

    // staging pointers (2 x 16B chunks per thread per buffer), swizzled source
    const unsigned short* gK[2]; const unsigned short* gV[2];
    int cs[2];
    #pragma unroll
    for (int i = 0; i < 2; ++i) {
        int c = i * 256 + tid;
        int row = c >> 3, ch = (c & 7) ^ (row & 7);
        cs[i] = c * 8;
        gK[i] = Kh + (size_t)(b * 1024 + row) * 1024 + h * 64 + ch * 8;
        gV[i] = Vt + (size_t)(bh * 64 + row) * 1024 + ch * 8;
    }

    int akoff[4][2];
    #pragma unroll
    for (int mf = 0; mf < 4; ++mf)
        #pragma unroll
        for (int kh = 0; kh < 2; ++kh)
            akoff[mf][kh] = (mf * 16 + rl) * 64 + (((kg + 4 * kh) ^ rl7) << 3);

    f32x4 o[4];
    #pragma unroll
    for (int i = 0; i < 4; ++i) { o[i][0]=0.f; o[i][1]=0.f; o[i][2]=0.f; o[i][3]=0.f; }
    float m_run = -3.0e38f, l_run = 0.f;
    const int nt = (klen == 1) ? (T_ / 64) : ((klen + 63) >> 6);

    for (int kb = 0; kb < nt; ++kb) {
        const int kbase = kb * 64;
        const size_t koff = (size_t)kbase * 1024;
        gl_lds16(gK[0] + koff, &KS[cs[0]]);
        gl_lds16(gK[1] + koff, &KS[cs[1]]);
        gl_lds16(gV[0] + kbase, &VtS[cs[0]]);
        gl_lds16(gV[1] + kbase, &VtS[cs[1]]);
        __syncthreads();

        // QK^T swapped: C[key][q]
        float v[4][4];
        #pragma unroll
        for (int mf = 0; mf < 4; ++mf) {
            f32x4 s; s[0]=0.f; s[1]=0.f; s[2]=0.f; s[3]=0.f;
            f16x8 a0 = *(const f16x8*)&KS[akoff[mf][0]];
            f16x8 a1 = *(const f16x8*)&KS[akoff[mf][1]];
            s = __builtin_amdgcn_mfma_f32_16x16x32_f16(a0, qb[0], s, 0, 0, 0);
            s = __builtin_amdgcn_mfma_f32_16x16x32_f16(a1, qb[1], s, 0, 0, 0);
            #pragma unroll
            for (int r = 0; r < 4; ++r) {
                int gk = kbase + mf * 16 + kg * 4 + r;
                float x = s[r] * 0.125f;
                if (gk >= klen || gk == gq) x = NEG_;
                v[mf][r] = x;
            }
        }
        // online softmax (per lane = one q-row; reduce across 4 lane-groups)
        float mt = -3.0e38f;
        #pragma unroll
        for (int mf = 0; mf < 4; ++mf)
            #pragma unroll
            for (int r = 0; r < 4; ++r) mt = fmaxf(mt, v[mf][r]);
        mt = fmaxf(mt, __shfl_xor(mt, 16));
        mt = fmaxf(mt, __shfl_xor(mt, 32));
        float mnew = fmaxf(m_run, mt);
        float fac = __expf(m_run - mnew);
        float sum = 0.f;
        #pragma unroll
        for (int mf = 0; mf < 4; ++mf) {
            ushort4 pb;
            pb.x = f2h(__expf(v[mf][0] - mnew));
            pb.y = f2h(__expf(v[mf][1] - mnew));
            pb.z = f2h(__expf(v[mf][2] - mnew));
            pb.w = f2h(__expf(v[mf][3] - mnew));
            sum += h2f(pb.x) + h2f(pb.y) + h2f(pb.z) + h2f(pb.w);
            *(ushort4*)&Pl[wq][rl * 72 + mf * 16 + kg * 4] = pb;
        }
        sum += __shfl_xor(sum, 16);
        sum += __shfl_xor(sum, 32);
        l_run = l_run * fac + sum;
        m_run = mnew;
        #pragma unroll
        for (int i = 0; i < 4; ++i) {
            o[i][0] *= fac; o[i][1] *= fac; o[i][2] *= fac; o[i][3] *= fac;
        }
        // PV: O^T[dh][q] += V^T-frag x P-frag
        f16x8 bp0 = *(const f16x8*)&Pl[wq][rl * 72 + kg * 8];
        f16x8 bp1 = *(const f16x8*)&Pl[wq][rl * 72 + 32 + kg * 8];
        #pragma unroll
        for (int dmf = 0; dmf < 4; ++dmf) {
            f16x8 a0 = *(const f16x8*)&VtS[akoff[dmf][0]];
            f16x8 a1 = *(const f16x8*)&VtS[akoff[dmf][1]];
            o[dmf] = __builtin_amdgcn_mfma_f32_16x16x32_f16(a0, bp0, o[dmf], 0, 0, 0);
            o[dmf] = __builtin_amdgcn_mfma_f32_16x16x32_f16(a1, bp1, o[dmf], 0, 0, 0);
        }
        __syncthreads();
    }

    // epilogue: lane holds col=q, rows dh = 16*dmf + 4*kg + r; RMW residual
    float invl = (gq < qlen) ? (1.f / l_run) : 0.f;
    #pragma unroll
    for (int dmf = 0; dmf < 4; ++dmf)
        #pragma unroll
        for (int r = 0; r < 4; ++r) {
            int dh = dmf * 16 + kg * 4 + r;
            size_t a = (size_t)(b * 1024 + gq) * 1024 + h * 64 + dh;
            q16[a] = f2h(o[dmf][r] * invl + h2f(q16[a]));
        }
}

// ---------------- mean over T of fp16 [4][1024][X] -> f32 [4][X] ----------------
__global__ __launch_bounds__(256) void mean16(const unsigned short* __restrict__ X,
                                              float* __restrict__ out, int Xdim)
{
    __shared__ float red[4][128];
    int tid = threadIdx.x;
    int b = blockIdx.y;
    int dbase = blockIdx.x * 128;
    int tq = tid >> 6, dd = tid & 63;
    int d = dbase + dd * 2;
    const unsigned short* p = X + ((size_t)b * T_ + tq * 256) * Xdim + d;
    float s0 = 0.f, s1 = 0.f;
    for (int t = 0; t < 256; ++t) {
        ushort2 v = *(const ushort2*)(p + (size_t)t * Xdim);
        s0 += h2f(v.x); s1 += h2f(v.y);
    }
    red[tq][dd*2] = s0; red[tq][dd*2 + 1] = s1;
    __syncthreads();
    if (tq == 0) {
        float a = red[0][dd*2] + red[1][dd*2] + red[2][dd*2] + red[3][dd*2];
        float c = red[0][dd*2+1] + red[1][dd*2+1] + red[2][dd*2+1] + red[3][dd*2+1];
        out[(size_t)b * Xdim + d]     = a * (1.f/1024.f);
        out[(size_t)b * Xdim + d + 1] = c * (1.f/1024.f);
    }
}

// ---- partial: Pout[jy][b][d] = sum_{j in 128-chunk jy} Hm[b][j]*fw2[j][d], jy in [0,32) ----
__global__ __launch_bounds__(256) void final_partial(const float* __restrict__ Hm,
                                                     const float* __restrict__ fw2,
                                                     float* __restrict__ Pout)
{
    __shared__ float red[4][4][64];
    int tid = threadIdx.x;
    int dd = tid & 63;
    int d = blockIdx.x * 64 + dd;
    int jq = tid >> 6;
    int j0 = blockIdx.y * 128 + jq * 32;
    float s[4] = {0.f, 0.f, 0.f, 0.f};
    for (int jj = 0; jj < 32; ++jj) {
        int j = j0 + jj;
        float wv = fw2[(size_t)j * 1024 + d];
        s[0] += Hm[j] * wv;
        s[1] += Hm[4096 + j] * wv;
        s[2] += Hm[8192 + j] * wv;
        s[3] += Hm[12288 + j] * wv;
    }
    #pragma unroll
    for (int bb = 0; bb < 4; ++bb) red[jq][bb][dd] = s[bb];
    __syncthreads();
    if (jq == 0) {
        #pragma unroll
        for (int bb = 0; bb < 4; ++bb) {
            float tot = red[0][bb][dd] + red[1][bb][dd] + red[2][bb][dd] + red[3][bb][dd];
            Pout[((size_t)blockIdx.y * 4 + bb) * 1024 + d] = tot;
        }
    }
}

// ---------------- out[b][d] = Mres[b][d] + sum_{jy<32} Pout[jy][b][d] ----------------
__global__ __launch_bounds__(256) void reduce_out(const float* __restrict__ Mres,
                                                  const float* __restrict__ Pout,
                                                  float* __restrict__ out)
{
    int idx = blockIdx.x * 256 + threadIdx.x;
    int b = idx >> 10, d = idx & 1023;
    float s = Mres[(size_t)b * 1024 + d];
    #pragma unroll
    for (int jy = 0; jy < 32; ++jy)
        s += Pout[((size_t)jy * 4 + b) * 1024 + d];
    out[(size_t)b * 1024 + d] = s;
}

extern "C" void kernel_launch(void* const* d_in, const int* in_sizes, int n_in,
                              void* d_out, int out_size, void* d_ws, size_t ws_size,
                              hipStream_t stream)
{
    const float* queries = (const float*)d_in[0];
    const int*   qlens   = (const int*)d_in[2];
    const int*   klens   = (const int*)d_in[3];
    const float* pe_q    = (const float*)d_in[4];
    const float* pe_k    = (const float*)d_in[5];
    const float* Wq      = (const float*)d_in[6];
    const float* Wk      = (const float*)d_in[7];
    const float* Wv      = (const float*)d_in[8];
    const float* fw1     = (const float*)d_in[9];
    const float* fw2     = (const float*)d_in[10];
    float* out = (float*)d_out;

    // arena (MB offsets), peak ~60 MB
    char* w = (char*)d_ws;
    unsigned short* Qh   = (unsigned short*)(w);                  // [0,8)
    unsigned short* A2   = (unsigned short*)(w + (8ll  << 20));   // [8,18)  rows 0..4095 = fp16(q_in)
    unsigned short* q16  = A2;                                    // [8,16)  aliases A2 rows 0..4095
    unsigned short* B2   = (unsigned short*)(w + (18ll << 20));   // [18,22)
    float*          Kraw = (float*)(w + (22ll << 20));            // [22,38)
    float*          PEKW = (float*)(w + (38ll << 20));            // [38,42)
    unsigned short* WvT  = (unsigned short*)(w + (16ll << 20));   // [16,18) over A2 pe-rows (dead post-QK)
    unsigned short* Vt   = (unsigned short*)(w + (18ll << 20));   // [18,26) over B2+Kraw-head (dead by V-GEMM)
    unsigned short* Kh16 = (unsigned short*)(w + (42ll << 20));   // [42,50)
    unsigned short* fw1T = (unsigned short*)(w + (50ll << 20));   // [50,58)
    unsigned short* h1   = (unsigned short*)(w + (18ll << 20));   // [18,50) post-attn (Vt/Kraw/PEKW/Kh16 dead)
    float*          Mres = (float*)(w + (58ll << 20));            // 16 KB
    float*          Hm   = (float*)(w + (58ll << 20) + (1ll << 18));  // 64 KB
    float*          Pout = (float*)(w + (59ll << 20));            // 512 KB

    // 1) conversions
    conv_af16 <<<4096, 256, 0, stream>>>(queries, pe_q, A2);
    conv_pef16<<<1024, 256, 0, stream>>>(pe_k, A2);
    conv_w2   <<<dim3(32, 32, 2), 256, 0, stream>>>(Wq, Wk, B2);
    // 2) stacked [Q|K|PEKW] GEMM: M=5120, N=2048, K=1024 fp16
    gemm_mfma<128><<<dim3(16, 40), 256, 0, stream>>>(
        A2, 1024, B2, 1024, 1024,
        Kraw, PEKW, Qh, 2048, 32);
    // 3) K fold + weight preps
    conv_kh<<<4096, 256, 0, stream>>>(Kraw, PEKW, Kh16);
    conv_wT<<<dim3(32, 32), 256, 0, stream>>>(Wv, WvT, 1024, 1024);
    conv_wT<<<dim3(128, 32), 256, 0, stream>>>(fw1, fw1T, 1024, 4096);
    // 4) V = Kh16 @ Wv, stored fp16 transposed Vt[b,h][dh][t]
    gemm_mfma<64><<<dim3(8, 64), 256, 0, stream>>>(
        Kh16, 1024, WvT, 1024, 1024,
        nullptr, nullptr, Vt, 1024, 64);
    // 5) MFMA attention + residual -> q16 in place
    attn_mfma<<<1024, 256, 0, stream>>>(Qh, Kh16, Vt, q16, qlens, klens);
    // 6) FFN1: h1 = relu(res @ fw1)
    gemm_mfma<128><<<dim3(32, 32), 256, 0, stream>>>(
        q16, 1024, fw1T, 1024, 1024,
        nullptr, nullptr, h1, 4096, 1 | 16);
    // 7) means + final: out = mean_t(res) + mean_t(h1) @ fw2
    mean16<<<dim3(8, 4),  256, 0, stream>>>(q16, Mres, 1024);
    mean16<<<dim3(32, 4), 256, 0, stream>>>(h1, Hm, 4096);
    final_partial<<<dim3(16, 32), 256, 0, stream>>>(Hm, fw2, Pout);
    reduce_out<<<16, 256, 0, stream>>>(Mres, Pout, out);
}

// Round 10
// 152.954 us; speedup vs baseline: 3.7981x; 1.3405x over previous
//
#include <hip/hip_runtime.h>

#define T_ 1024
#define D_ 1024
#define B_ 4
#define H_ 16
#define DH_ 64
#define M_ (B_*T_)                 // 4096
#define NEG_ (-4294967295.0f)

typedef __attribute__((ext_vector_type(8))) _Float16 f16x8;
typedef __attribute__((ext_vector_type(4))) float f32x4;

__device__ __forceinline__ unsigned short f2h(float f) {
    _Float16 h = (_Float16)f; unsigned short u; __builtin_memcpy(&u, &h, 2); return u;
}
__device__ __forceinline__ float h2f(unsigned short u) {
    _Float16 h; __builtin_memcpy(&h, &u, 2); return (float)h;
}

typedef const unsigned int __attribute__((address_space(1)))* gas_p;
typedef unsigned int __attribute__((address_space(3)))* las_p;
__device__ __forceinline__ void gl_lds16(const void* g, void* l) {
    __builtin_amdgcn_global_load_lds((gas_p)g, (las_p)l, 16, 0, 0);
}

// ---- conv: A2 rows 0..4095 = fp16(q_in) [doubles as q16]; rows 4096..5119 = fp16(32*pe_k) ----
__global__ __launch_bounds__(256) void conv_a(const float* __restrict__ q,
                                              const float* __restrict__ peq,
                                              const float* __restrict__ pek,
                                              unsigned short* __restrict__ A2)
{
    int i = blockIdx.x * 256 + threadIdx.x;
    int m = i >> 8, c4 = (i & 255) << 2;
    ushort4 h;
    if (m < 4096) {
        float4 qv = *(const float4*)(q + (size_t)m * D_ + c4);
        float4 p  = *(const float4*)(peq + (size_t)(m & (T_-1)) * D_ + c4);
        h.x = f2h(qv.x + 32.f*p.x); h.y = f2h(qv.y + 32.f*p.y);
        h.z = f2h(qv.z + 32.f*p.z); h.w = f2h(qv.w + 32.f*p.w);
    } else {
        float4 p = *(const float4*)(pek + (size_t)(m - 4096) * D_ + c4);
        h.x = f2h(32.f*p.x); h.y = f2h(32.f*p.y);
        h.z = f2h(32.f*p.z); h.w = f2h(32.f*p.w);
    }
    *(ushort4*)(A2 + (size_t)m * 1024 + c4) = h;
}

// ---------------- conv: [Wq|Wk] -> B2[n][k] fp16, n in [0,2048) ----------------
__global__ __launch_bounds__(256) void conv_w2(const float* __restrict__ Wq,
                                               const float* __restrict__ Wk,
                                               unsigned short* __restrict__ B2)
{
    __shared__ float t[32][33];
    const float* W = blockIdx.z ? Wk : Wq;
    int k0 = blockIdx.y * 32, n0 = blockIdx.x * 32;
    int r = threadIdx.x >> 5, c = threadIdx.x & 31;
    #pragma unroll
    for (int rr = 0; rr < 4; ++rr)
        t[r + 8*rr][c] = W[(size_t)(k0 + r + 8*rr) * 1024 + n0 + c];
    __syncthreads();
    #pragma unroll
    for (int rr = 0; rr < 4; ++rr)
        B2[(size_t)(blockIdx.z * 1024 + n0 + r + 8*rr) * 1024 + k0 + c] = f2h(t[c][r + 8*rr]);
}

// ---------------- conv: WT[n][k] = fp16(W[k][n]) ----------------
__global__ __launch_bounds__(256) void conv_wT(const float* __restrict__ W,
                                               unsigned short* __restrict__ WT,
                                               int K, int N)
{
    __shared__ float t[32][33];
    int k0 = blockIdx.y * 32, n0 = blockIdx.x * 32;
    int r = threadIdx.x >> 5, c = threadIdx.x & 31;
    #pragma unroll
    for (int rr = 0; rr < 4; ++rr)
        t[r + 8*rr][c] = W[(size_t)(k0 + r + 8*rr) * N + n0 + c];
    __syncthreads();
    #pragma unroll
    for (int rr = 0; rr < 4; ++rr)
        WT[(size_t)(n0 + r + 8*rr) * K + k0 + c] = f2h(t[c][r + 8*rr]);
}

// ---------------- conv: Kh16 = fp16(Kraw + PEKW) ----------------
__global__ __launch_bounds__(256) void conv_kh(const float* __restrict__ Kraw,
                                               const float* __restrict__ pekw,
                                               unsigned short* __restrict__ Kh16)
{
    int i = blockIdx.x * 256 + threadIdx.x;
    int m = i >> 8, c4 = (i & 255) << 2;
    float4 kv = *(const float4*)(Kraw + (size_t)m * D_ + c4);
    float4 p  = *(const float4*)(pekw + (size_t)(m & (T_-1)) * D_ + c4);
    ushort4 h;
    h.x = f2h(kv.x + p.x); h.y = f2h(kv.y + p.y);
    h.z = f2h(kv.z + p.z); h.w = f2h(kv.w + p.w);
    *(ushort4*)(Kh16 + (size_t)m * 1024 + c4) = h;
}

// ---------------- counted-vmcnt pipelined fp16 MFMA GEMM, coalesced+swizzled staging ----
// flags: 1 relu | 8 store-f32 | 16 store-fp16 | 32 stacked-QK epilogue (+len skip)
//      | 64 V-transposed-fp16 | 128 FFN1 colsum->hpart | 256 row-skip via klens
template<int BM>
__global__ __launch_bounds__(256) void gemm_mfma(
    const unsigned short* __restrict__ A, int lda,
    const unsigned short* __restrict__ B, int ldb, int K,
    float* __restrict__ outf, float* __restrict__ outp,
    unsigned short* __restrict__ outh, int N, int flags,
    const int* __restrict__ qlv, const int* __restrict__ klv,
    float* __restrict__ hpart)
{
    constexpr int WN = (BM == 128) ? 2 : 4;
    constexpr int FN = 8 / WN;
    constexpr int NA = BM / 32;
    __shared__ __align__(16) unsigned short As[2][BM * 64];
    __shared__ __align__(16) unsigned short Bs[2][128 * 64];
    __shared__ float hp[4][64];
    const int tid = threadIdx.x;
    const int m0 = blockIdx.y * BM, n0 = blockIdx.x << 7;
    // ---- length-aware block skipping ----
    if (flags & 32) {
        if (m0 >= 4096) {
            if (n0 < 1024) return;                      // pe-rows x Q-cols: garbage
        } else {
            int bb = m0 >> 10, t0 = m0 & 1023;
            if (n0 < 1024) { if (t0 >= qlv[bb]) return; }          // Q never read past qlen
            else { int kl = klv[bb]; if (kl > 1 && t0 >= kl) return; }  // K/V never read past klen
        }
    }
    if (flags & 256) {
        int bb = m0 >> 10, kl = klv[bb];
        if (kl > 1 && (m0 & 1023) >= kl) return;
    }
    const int lane = tid & 63, wave = tid >> 6;
    const int wm = (wave / WN) * 64;
    const int wn = (wave % WN) * (128 / WN);
    const int rl = lane & 15, kg = lane >> 4;
    const int rl7 = lane & 7;

    int ca[NA]; const unsigned short* gA[NA];
    #pragma unroll
    for (int i = 0; i < NA; ++i) {
        int c = i * 256 + tid;
        int row = c >> 3, k8 = (c & 7) ^ (row & 7);
        ca[i] = c * 8;
        gA[i] = A + (size_t)(m0 + row) * lda + k8 * 8;
    }
    int cb[4]; const unsigned short* gB[4];
    #pragma unroll
    for (int i = 0; i < 4; ++i) {
        int c = i * 256 + tid;
        int row = c >> 3, k8 = (c & 7) ^ (row & 7);
        cb[i] = c * 8;
        gB[i] = B + (size_t)(n0 + row) * ldb + k8 * 8;
    }

    int aoff[2][4], boff[2][FN];
    #pragma unroll
    for (int tt = 0; tt < 2; ++tt) {
        #pragma unroll
        for (int f = 0; f < 4; ++f)
            aoff[tt][f] = (wm + (f << 4) + rl) * 64 + (((tt * 4 + kg) ^ rl7) << 3);
        #pragma unroll
        for (int f = 0; f < FN; ++f)
            boff[tt][f] = (wn + (f << 4) + rl) * 64 + (((tt * 4 + kg) ^ rl7) << 3);
    }

    f32x4 acc[4][FN];
    #pragma unroll
    for (int i = 0; i < 4; ++i)
        #pragma unroll
        for (int j = 0; j < FN; ++j) {
            acc[i][j][0] = 0.f; acc[i][j][1] = 0.f;
            acc[i][j][2] = 0.f; acc[i][j][3] = 0.f;
        }

    const int NT = K >> 6;
    #pragma unroll
    for (int i = 0; i < 4; ++i)  gl_lds16(gB[i], &Bs[0][cb[i]]);
    #pragma unroll
    for (int i = 0; i < NA; ++i) gl_lds16(gA[i], &As[0][ca[i]]);
    #pragma unroll
    for (int i = 0; i < 4; ++i)  gl_lds16(gB[i] + 64, &Bs[1][cb[i]]);
    #pragma unroll
    for (int i = 0; i < NA; ++i) gl_lds16(gA[i] + 64, &As[1][ca[i]]);

    for (int t = 0; t < NT; ++t) {
        const int cur = t & 1;
        if (t + 1 < NT) {
            if constexpr (BM == 128) asm volatile("s_waitcnt vmcnt(8)" ::: "memory");
            else                     asm volatile("s_waitcnt vmcnt(6)" ::: "memory");
        } else {
            asm volatile("s_waitcnt vmcnt(0)" ::: "memory");
        }
        __builtin_amdgcn_s_barrier();
        __builtin_amdgcn_sched_barrier(0);
        f16x8 av[2][4], bv[2][FN];
        #pragma unroll
        for (int tt = 0; tt < 2; ++tt) {
            #pragma unroll
            for (int f = 0; f < 4; ++f)
                av[tt][f] = *(const f16x8*)&As[cur][aoff[tt][f]];
            #pragma unroll
            for (int f = 0; f < FN; ++f)
                bv[tt][f] = *(const f16x8*)&Bs[cur][boff[tt][f]];
        }
        asm volatile("s_waitcnt lgkmcnt(0)" ::: "memory");
        __builtin_amdgcn_sched_barrier(0);
        __builtin_amdgcn_s_barrier();
        __builtin_amdgcn_sched_barrier(0);
        if (t + 2 < NT) {
            const int ko = (t + 2) << 6;
            #pragma unroll
            for (int i = 0; i < 4; ++i)  gl_lds16(gB[i] + ko, &Bs[cur][cb[i]]);
            #pragma unroll
            for (int i = 0; i < NA; ++i) gl_lds16(gA[i] + ko, &As[cur][ca[i]]);
        }
        #pragma unroll
        for (int fm = 0; fm < 4; ++fm)
            #pragma unroll
            for (int fn = 0; fn < FN; ++fn) {
                acc[fm][fn] = __builtin_amdgcn_mfma_f32_16x16x32_f16(av[0][fm], bv[0][fn], acc[fm][fn], 0, 0, 0);
                acc[fm][fn] = __builtin_amdgcn_mfma_f32_16x16x32_f16(av[1][fm], bv[1][fn], acc[fm][fn], 0, 0, 0);
            }
    }

    // ---- FFN1 colsum epilogue: Hpart[mb][n] = sum over block's 128 rows of relu(x) ----
    if (flags & 128) {
        if constexpr (BM == 128) {
            #pragma unroll
            for (int fn = 0; fn < FN; ++fn) {
                float p = 0.f;
                #pragma unroll
                for (int fm = 0; fm < 4; ++fm)
                    #pragma unroll
                    for (int r = 0; r < 4; ++r) p += fmaxf(acc[fm][fn][r], 0.f);
                p += __shfl_xor(p, 16);
                p += __shfl_xor(p, 32);
                if (kg == 0) hp[wave][fn * 16 + rl] = p;
            }
            __syncthreads();
            if (tid < 128) {
                int c = tid;
                float s = (c < 64) ? (hp[0][c] + hp[2][c]) : (hp[1][c - 64] + hp[3][c - 64]);
                hpart[(size_t)blockIdx.y * 4096 + n0 + c] = s;
            }
        }
        return;
    }

    // ---- standard epilogue: C/D layout col=lane&15, row=(lane>>4)*4+reg ----
    #pragma unroll
    for (int fm = 0; fm < 4; ++fm) {
        int row = m0 + wm + (fm << 4) + (kg << 2);
        #pragma unroll
        for (int fn = 0; fn < FN; ++fn) {
            int col = n0 + wn + (fn << 4) + rl;
            if (flags & 64) {
                ushort4 u;
                u.x = f2h(acc[fm][fn][0]); u.y = f2h(acc[fm][fn][1]);
                u.z = f2h(acc[fm][fn][2]); u.w = f2h(acc[fm][fn][3]);
                size_t a = ((size_t)((row >> 10) * 16 + (col >> 6)) * 64 + (col & 63)) * 1024 + (row & 1023);
                *(ushort4*)(outh + a) = u;
                continue;
            }
            #pragma unroll
            for (int r = 0; r < 4; ++r) {
                float x = acc[fm][fn][r];
                int rr = row + r;
                if (flags & 32) {
                    if (rr < 4096) {
                        if (col < 1024) outh[(size_t)rr * 1024 + col] = f2h(x);          // Q fp16
                        else            outf[(size_t)rr * 1024 + (col - 1024)] = x;      // Kraw f32
                    } else if (col >= 1024) {
                        outp[(size_t)(rr - 4096) * 1024 + (col - 1024)] = x;             // PEKW
                    }
                } else {
                    size_t idx = (size_t)rr * N + col;
                    if (flags & 1)  x = fmaxf(x, 0.f);
                    if (flags & 8)  outf[idx] = x;
                    if (flags & 16) outh[idx] = f2h(x);
                }
            }
        }
    }
}

// ---------------- MFMA flash attention (swapped QK, fp16) ----------------
__global__ __launch_bounds__(256) void attn_mfma(
    const unsigned short* __restrict__ Qh,
    const unsigned short* __restrict__ Kh,
    const unsigned short* __restrict__ Vt,
    unsigned short* __restrict__ q16,
    const int* __restrict__ qlens, const int* __restrict__ klens)
{
    __shared__ __align__(16) unsigned short KS[4096];
    __shared__ __align__(16) unsigned short VtS[4096];
    __shared__ __align__(16) unsigned short Pl[4][1152];

    const int tid = threadIdx.x;
    const int bh = blockIdx.x & 63;
    const int qt = blockIdx.x >> 6;
    const int b = bh >> 4, h = bh & 15;
    const int qbase = qt * 64;
    const int qlen = qlens[b], klen = klens[b];
    if (qbase >= qlen) return;

    const int lane = tid & 63, wq = tid >> 6;
    const int rl = lane & 15, kg = lane >> 4, rl7 = lane & 7;
    const int gq = qbase + wq * 16 + rl;

    f16x8 qb[2];
    {
        const unsigned short* p1 = Qh + (size_t)(b * 1024 + gq) * 1024 + h * 64 + kg * 8;
        qb[0] = *(const f16x8*)p1;  qb[1] = *(const f16x8*)(p1 + 32);
    }

    const unsigned short* gK[2]; const unsigned short* gV[2];
    int cs[2];
    #pragma unroll
    for (int i = 0; i < 2; ++i) {
        int c = i * 256 + tid;
        int row = c >> 3, ch = (c & 7) ^ (row & 7);
        cs[i] = c * 8;
        gK[i] = Kh + (size_t)(b * 1024 + row) * 1024 + h * 64 + ch * 8;
        gV[i] = Vt + (size_t)(bh * 64 + row) * 1024 + ch * 8;
    }

    int akoff[4][2];
    #pragma unroll
    for (int mf = 0; mf < 4; ++mf)
        #pragma unroll
        for (int kh = 0; kh < 2; ++kh)
            akoff[mf][kh] = (mf * 16 + rl) * 64 + (((kg + 4 * kh) ^ rl7) << 3);

    f32x4 o[4];
    #pragma unroll
    for (int i = 0; i < 4; ++i) { o[i][0]=0.f; o[i][1]=0.f; o[i][2]=0.f; o[i][3]=0.f; }
    float m_run = -3.0e38f, l_run = 0.f;
    const int nt = (klen == 1) ? (T_ / 64) : ((klen + 63) >> 6);

    for (int kb = 0; kb < nt; ++kb) {
        const int kbase = kb * 64;
        const size_t koff = (size_t)kbase * 1024;
        gl_lds16(gK[0] + koff, &KS[cs[0]]);
        gl_lds16(gK[1] + koff, &KS[cs[1]]);
        gl_lds16(gV[0] + kbase, &VtS[cs[0]]);
        gl_lds16(gV[1] + kbase, &VtS[cs[1]]);
        __syncthreads();

        float v[4][4];
        #pragma unroll
        for (int mf = 0; mf < 4; ++mf) {
            f32x4 s; s[0]=0.f; s[1]=0.f; s[2]=0.f; s[3]=0.f;
            f16x8 a0 = *(const f16x8*)&KS[akoff[mf][0]];
            f16x8 a1 = *(const f16x8*)&KS[akoff[mf][1]];
            s = __builtin_amdgcn_mfma_f32_16x16x32_f16(a0, qb[0], s, 0, 0, 0);
            s = __builtin_amdgcn_mfma_f32_16x16x32_f16(a1, qb[1], s, 0, 0, 0);
            #pragma unroll
            for (int r = 0; r < 4; ++r) {
                int gk = kbase + mf * 16 + kg * 4 + r;
                float x = s[r] * 0.125f;
                if (gk >= klen || gk == gq) x = NEG_;
                v[mf][r] = x;
            }
        }
        float mt = -3.0e38f;
        #pragma unroll
        for (int mf = 0; mf < 4; ++mf)
            #pragma unroll
            for (int r = 0; r < 4; ++r) mt = fmaxf(mt, v[mf][r]);
        mt = fmaxf(mt, __shfl_xor(mt, 16));
        mt = fmaxf(mt, __shfl_xor(mt, 32));
        float mnew = fmaxf(m_run, mt);
        float fac = __expf(m_run - mnew);
        float sum = 0.f;
        #pragma unroll
        for (int mf = 0; mf < 4; ++mf) {
            ushort4 pb;
            pb.x = f2h(__expf(v[mf][0] - mnew));
            pb.y = f2h(__expf(v[mf][1] - mnew));
            pb.z = f2h(__expf(v[mf][2] - mnew));
            pb.w = f2h(__expf(v[mf][3] - mnew));
            sum += h2f(pb.x) + h2f(pb.y) + h2f(pb.z) + h2f(pb.w);
            *(ushort4*)&Pl[wq][rl * 72 + mf * 16 + kg * 4] = pb;
        }
        sum += __shfl_xor(sum, 16);
        sum += __shfl_xor(sum, 32);
        l_run = l_run * fac + sum;
        m_run = mnew;
        #pragma unroll
        for (int i = 0; i < 4; ++i) {
            o[i][0] *= fac; o[i][1] *= fac; o[i][2] *= fac; o[i][3] *= fac;
        }
        f16x8 bp0 = *(const f16x8*)&Pl[wq][rl * 72 + kg * 8];
        f16x8 bp1 = *(const f16x8*)&Pl[wq][rl * 72 + 32 + kg * 8];
        #pragma unroll
        for (int dmf = 0; dmf < 4; ++dmf) {
            f16x8 a0 = *(const f16x8*)&VtS[akoff[dmf][0]];
            f16x8 a1 = *(const f16x8*)&VtS[akoff[dmf][1]];
            o[dmf] = __builtin_amdgcn_mfma_f32_16x16x32_f16(a0, bp0, o[dmf], 0, 0, 0);
            o[dmf] = __builtin_amdgcn_mfma_f32_16x16x32_f16(a1, bp1, o[dmf], 0, 0, 0);
        }
        __syncthreads();
    }

    float invl = (gq < qlen) ? (1.f / l_run) : 0.f;
    #pragma unroll
    for (int dmf = 0; dmf < 4; ++dmf)
        #pragma unroll
        for (int r = 0; r < 4; ++r) {
            int dh = dmf * 16 + kg * 4 + r;
            size_t a = (size_t)(b * 1024 + gq) * 1024 + h * 64 + dh;
            q16[a] = f2h(o[dmf][r] * invl + h2f(q16[a]));
        }
}

// ---------------- mean over T of fp16 [4][1024][X] -> f32 [4][X] ----------------
__global__ __launch_bounds__(256) void mean16(const unsigned short* __restrict__ X,
                                              float* __restrict__ out, int Xdim)
{
    __shared__ float red[4][128];
    int tid = threadIdx.x;
    int b = blockIdx.y;
    int dbase = blockIdx.x * 128;
    int tq = tid >> 6, dd = tid & 63;
    int d = dbase + dd * 2;
    const unsigned short* p = X + ((size_t)b * T_ + tq * 256) * Xdim + d;
    float s0 = 0.f, s1 = 0.f;
    for (int t = 0; t < 256; ++t) {
        ushort2 v = *(const ushort2*)(p + (size_t)t * Xdim);
        s0 += h2f(v.x); s1 += h2f(v.y);
    }
    red[tq][dd*2] = s0; red[tq][dd*2 + 1] = s1;
    __syncthreads();
    if (tq == 0) {
        float a = red[0][dd*2] + red[1][dd*2] + red[2][dd*2] + red[3][dd*2];
        float c = red[0][dd*2+1] + red[1][dd*2+1] + red[2][dd*2+1] + red[3][dd*2+1];
        out[(size_t)b * Xdim + d]     = a * (1.f/1024.f);
        out[(size_t)b * Xdim + d + 1] = c * (1.f/1024.f);
    }
}

// ---------------- Hm[b][j] = (1/1024) * sum_{i<8} Hpart[b*8+i][j] ----------------
__global__ __launch_bounds__(256) void hm_reduce(const float* __restrict__ Hpart,
                                                 float* __restrict__ Hm)
{
    int idx = blockIdx.x * 256 + threadIdx.x;   // 16384 total
    int b = idx >> 12, j = idx & 4095;
    float s = 0.f;
    #pragma unroll
    for (int i = 0; i < 8; ++i)
        s += Hpart[((size_t)(b * 8 + i)) * 4096 + j];
    Hm[(size_t)b * 4096 + j] = s * (1.f / 1024.f);
}

// ---- partial: Pout[jy][b][d] = sum_{j in 128-chunk jy} Hm[b][j]*fw2[j][d], jy in [0,32) ----
__global__ __launch_bounds__(256) void final_partial(const float* __restrict__ Hm,
                                                     const float* __restrict__ fw2,
                                                     float* __restrict__ Pout)
{
    __shared__ float red[4][4][64];
    int tid = threadIdx.x;
    int dd = tid & 63;
    int d = blockIdx.x * 64 + dd;
    int jq = tid >> 6;
    int j0 = blockIdx.y * 128 + jq * 32;
    float s[4] = {0.f, 0.f, 0.f, 0.f};
    for (int jj = 0; jj < 32; ++jj) {
        int j = j0 + jj;
        float wv = fw2[(size_t)j * 1024 + d];
        s[0] += Hm[j] * wv;
        s[1] += Hm[4096 + j] * wv;
        s[2] += Hm[8192 + j] * wv;
        s[3] += Hm[12288 + j] * wv;
    }
    #pragma unroll
    for (int bb = 0; bb < 4; ++bb) red[jq][bb][dd] = s[bb];
    __syncthreads();
    if (jq == 0) {
        #pragma unroll
        for (int bb = 0; bb < 4; ++bb) {
            float tot = red[0][bb][dd] + red[1][bb][dd] + red[2][bb][dd] + red[3][bb][dd];
            Pout[((size_t)blockIdx.y * 4 + bb) * 1024 + d] = tot;
        }
    }
}

// ---------------- out[b][d] = Mres[b][d] + sum_{jy<32} Pout[jy][b][d] ----------------
__global__ __launch_bounds__(256) void reduce_out(const float* __restrict__ Mres,
                                                  const float* __restrict__ Pout,
                                                  float* __restrict__ out)
{
    int idx = blockIdx.x * 256 + threadIdx.x;
    int b = idx >> 10, d = idx & 1023;
    float s = Mres[(size_t)b * 1024 + d];
    #pragma unroll
    for (int jy = 0; jy < 32; ++jy)
        s += Pout[((size_t)jy * 4 + b) * 1024 + d];
    out[(size_t)b * 1024 + d] = s;
}

extern "C" void kernel_launch(void* const* d_in, const int* in_sizes, int n_in,
                              void* d_out, int out_size, void* d_ws, size_t ws_size,
                              hipStream_t stream)
{
    const float* queries = (const float*)d_in[0];
    const int*   qlens   = (const int*)d_in[2];
    const int*   klens   = (const int*)d_in[3];
    const float* pe_q    = (const float*)d_in[4];
    const float* pe_k    = (const float*)d_in[5];
    const float* Wq      = (const float*)d_in[6];
    const float* Wk      = (const float*)d_in[7];
    const float* Wv      = (const float*)d_in[8];
    const float* fw1     = (const float*)d_in[9];
    const float* fw2     = (const float*)d_in[10];
    float* out = (float*)d_out;

    // arena (MB offsets), peak ~60 MB
    char* w = (char*)d_ws;
    unsigned short* Qh   = (unsigned short*)(w);                  // [0,8)
    unsigned short* A2   = (unsigned short*)(w + (8ll  << 20));   // [8,18)  rows 0..4095 = fp16(q_in)
    unsigned short* q16  = A2;                                    // [8,16)  aliases A2 rows 0..4095
    unsigned short* B2   = (unsigned short*)(w + (18ll << 20));   // [18,22)
    float*          Kraw = (float*)(w + (22ll << 20));            // [22,38)
    float*          PEKW = (float*)(w + (38ll << 20));            // [38,42)
    unsigned short* WvT  = (unsigned short*)(w + (16ll << 20));   // [16,18) over A2 pe-rows (dead post-QK)
    unsigned short* Vt   = (unsigned short*)(w + (18ll << 20));   // [18,26) over B2+Kraw-head (dead by V-GEMM)
    unsigned short* Kh16 = (unsigned short*)(w + (42ll << 20));   // [42,50)
    unsigned short* fw1T = (unsigned short*)(w + (50ll << 20));   // [50,58)
    float*          Hpart= (float*)(w + (58ll << 20));            // 512 KB: [32 mb][4096 n]
    float*          Mres = (float*)(w + (59ll << 20));            // 16 KB
    float*          Hm   = (float*)(w + (59ll << 20) + (1ll << 18)); // 64 KB
    float*          Pout = (float*)(w + (60ll << 20));            // 512 KB

    // 1) conversions
    conv_a <<<5120, 256, 0, stream>>>(queries, pe_q, pe_k, A2);
    conv_w2<<<dim3(32, 32, 2), 256, 0, stream>>>(Wq, Wk, B2);
    // 2) stacked [Q|K|PEKW] GEMM: M=5120, N=2048, K=1024 fp16 (length-aware skip)
    gemm_mfma<128><<<dim3(16, 40), 256, 0, stream>>>(
        A2, 1024, B2, 1024, 1024,
        Kraw, PEKW, Qh, 2048, 32, qlens, klens, nullptr);
    // 3) K fold + weight preps
    conv_kh<<<4096, 256, 0, stream>>>(Kraw, PEKW, Kh16);
    conv_wT<<<dim3(32, 32), 256, 0, stream>>>(Wv, WvT, 1024, 1024);
    conv_wT<<<dim3(128, 32), 256, 0, stream>>>(fw1, fw1T, 1024, 4096);
    // 4) V = Kh16 @ Wv, stored fp16 transposed Vt[b,h][dh][t]  (length-aware skip)
    gemm_mfma<64><<<dim3(8, 64), 256, 0, stream>>>(
        Kh16, 1024, WvT, 1024, 1024,
        nullptr, nullptr, Vt, 1024, 64 | 256, nullptr, klens, nullptr);
    // 5) MFMA attention + residual -> q16 in place
    attn_mfma<<<1024, 256, 0, stream>>>(Qh, Kh16, Vt, q16, qlens, klens);
    // 6) FFN1 fused colsum: Hpart[mb][n] = sum_rows relu(res @ fw1)  (h1 never stored)
    gemm_mfma<128><<<dim3(32, 32), 256, 0, stream>>>(
        q16, 1024, fw1T, 1024, 1024,
        nullptr, nullptr, nullptr, 4096, 128, nullptr, nullptr, Hpart);
    // 7) means + final: out = mean_t(res) + mean_t(h1) @ fw2
    mean16<<<dim3(8, 4), 256, 0, stream>>>(q16, Mres, 1024);
    hm_reduce<<<64, 256, 0, stream>>>(Hpart, Hm);
    final_partial<<<dim3(16, 32), 256, 0, stream>>>(Hm, fw2, Pout);
    reduce_out<<<16, 256, 0, stream>>>(Mres, Pout, out);
}

// Round 11
// 144.841 us; speedup vs baseline: 4.0108x; 1.0560x over previous
//
#include <hip/hip_runtime.h>

#define T_ 1024
#define D_ 1024
#define B_ 4
#define H_ 16
#define DH_ 64
#define M_ (B_*T_)                 // 4096
#define NEG_ (-4294967295.0f)

typedef __attribute__((ext_vector_type(8))) _Float16 f16x8;
typedef __attribute__((ext_vector_type(4))) float f32x4;

__device__ __forceinline__ unsigned short f2h(float f) {
    _Float16 h = (_Float16)f; unsigned short u; __builtin_memcpy(&u, &h, 2); return u;
}
__device__ __forceinline__ float h2f(unsigned short u) {
    _Float16 h; __builtin_memcpy(&h, &u, 2); return (float)h;
}

typedef const unsigned int __attribute__((address_space(1)))* gas_p;
typedef unsigned int __attribute__((address_space(3)))* las_p;
__device__ __forceinline__ void gl_lds16(const void* g, void* l) {
    __builtin_amdgcn_global_load_lds((gas_p)g, (las_p)l, 16, 0, 0);
}

// ---- conv: A2 rows 0..4095 = fp16(q_in) [doubles as q16];
//            rows 4096..8191 = fp16(q_in + 32*pe_k)  (= k_in) ----
__global__ __launch_bounds__(256) void conv_a(const float* __restrict__ q,
                                              const float* __restrict__ peq,
                                              const float* __restrict__ pek,
                                              unsigned short* __restrict__ A2)
{
    int i = blockIdx.x * 256 + threadIdx.x;
    int m = i >> 8, c4 = (i & 255) << 2;
    ushort4 h;
    int mq = m & 4095;
    float4 qv = *(const float4*)(q + (size_t)mq * D_ + c4);
    float4 p  = *(const float4*)(peq + (size_t)(m & (T_-1)) * D_ + c4);
    if (m < 4096) {
        h.x = f2h(qv.x + 32.f*p.x); h.y = f2h(qv.y + 32.f*p.y);
        h.z = f2h(qv.z + 32.f*p.z); h.w = f2h(qv.w + 32.f*p.w);
    } else {
        float4 pk = *(const float4*)(pek + (size_t)(m & (T_-1)) * D_ + c4);
        h.x = f2h(qv.x + 32.f*(p.x + pk.x)); h.y = f2h(qv.y + 32.f*(p.y + pk.y));
        h.z = f2h(qv.z + 32.f*(p.z + pk.z)); h.w = f2h(qv.w + 32.f*(p.w + pk.w));
    }
    *(ushort4*)(A2 + (size_t)m * 1024 + c4) = h;
}

// ---------------- conv: [Wq|Wk] -> B2[n][k] fp16, n in [0,2048) ----------------
__global__ __launch_bounds__(256) void conv_w2(const float* __restrict__ Wq,
                                               const float* __restrict__ Wk,
                                               unsigned short* __restrict__ B2)
{
    __shared__ float t[32][33];
    const float* W = blockIdx.z ? Wk : Wq;
    int k0 = blockIdx.y * 32, n0 = blockIdx.x * 32;
    int r = threadIdx.x >> 5, c = threadIdx.x & 31;
    #pragma unroll
    for (int rr = 0; rr < 4; ++rr)
        t[r + 8*rr][c] = W[(size_t)(k0 + r + 8*rr) * 1024 + n0 + c];
    __syncthreads();
    #pragma unroll
    for (int rr = 0; rr < 4; ++rr)
        B2[(size_t)(blockIdx.z * 1024 + n0 + r + 8*rr) * 1024 + k0 + c] = f2h(t[c][r + 8*rr]);
}

// ---------------- conv: WT[n][k] = fp16(W[k][n]) ----------------
__global__ __launch_bounds__(256) void conv_wT(const float* __restrict__ W,
                                               unsigned short* __restrict__ WT,
                                               int K, int N)
{
    __shared__ float t[32][33];
    int k0 = blockIdx.y * 32, n0 = blockIdx.x * 32;
    int r = threadIdx.x >> 5, c = threadIdx.x & 31;
    #pragma unroll
    for (int rr = 0; rr < 4; ++rr)
        t[r + 8*rr][c] = W[(size_t)(k0 + r + 8*rr) * N + n0 + c];
    __syncthreads();
    #pragma unroll
    for (int rr = 0; rr < 4; ++rr)
        WT[(size_t)(n0 + r + 8*rr) * K + k0 + c] = f2h(t[c][r + 8*rr]);
}

// ---------------- counted-vmcnt pipelined fp16 MFMA GEMM, coalesced+swizzled staging ----
// flags: 1 relu | 8 store-f32 | 16 store-fp16 | 32 stacked-QK epilogue (+len skip)
//      | 64 V-transposed-fp16 | 128 FFN1 colsum->hpart | 256 row-skip via klens
template<int BM>
__global__ __launch_bounds__(256) void gemm_mfma(
    const unsigned short* __restrict__ A, int lda,
    const unsigned short* __restrict__ B, int ldb, int K,
    float* __restrict__ outf,
    unsigned short* __restrict__ outh, unsigned short* __restrict__ outh2,
    int N, int flags,
    const int* __restrict__ qlv, const int* __restrict__ klv,
    float* __restrict__ hpart)
{
    constexpr int WN = (BM == 128) ? 2 : 4;
    constexpr int FN = 8 / WN;
    constexpr int NA = BM / 32;
    __shared__ __align__(16) unsigned short As[2][BM * 64];
    __shared__ __align__(16) unsigned short Bs[2][128 * 64];
    __shared__ float hp[4][64];
    const int tid = threadIdx.x;
    const int m0 = blockIdx.y * BM, n0 = blockIdx.x << 7;
    // ---- length-aware block skipping ----
    if (flags & 32) {
        if (m0 < 4096) {                               // q_in rows -> Q cols only
            if (n0 >= 1024) return;
            if ((m0 & 1023) >= qlv[m0 >> 10]) return;
        } else {                                       // k_in rows -> K cols only
            if (n0 < 1024) return;
            if ((m0 & 1023) >= klv[(m0 - 4096) >> 10]) return;  // mask-safe even klen==1
        }
    }
    if (flags & 256) {
        int bb = m0 >> 10, kl = klv[bb];
        if (kl > 1 && (m0 & 1023) >= kl) return;       // V: klen==1 needs ALL rows
    }
    const int lane = tid & 63, wave = tid >> 6;
    const int wm = (wave / WN) * 64;
    const int wn = (wave % WN) * (128 / WN);
    const int rl = lane & 15, kg = lane >> 4;
    const int rl7 = lane & 7;

    int ca[NA]; const unsigned short* gA[NA];
    #pragma unroll
    for (int i = 0; i < NA; ++i) {
        int c = i * 256 + tid;
        int row = c >> 3, k8 = (c & 7) ^ (row & 7);
        ca[i] = c * 8;
        gA[i] = A + (size_t)(m0 + row) * lda + k8 * 8;
    }
    int cb[4]; const unsigned short* gB[4];
    #pragma unroll
    for (int i = 0; i < 4; ++i) {
        int c = i * 256 + tid;
        int row = c >> 3, k8 = (c & 7) ^ (row & 7);
        cb[i] = c * 8;
        gB[i] = B + (size_t)(n0 + row) * ldb + k8 * 8;
    }

    int aoff[2][4], boff[2][FN];
    #pragma unroll
    for (int tt = 0; tt < 2; ++tt) {
        #pragma unroll
        for (int f = 0; f < 4; ++f)
            aoff[tt][f] = (wm + (f << 4) + rl) * 64 + (((tt * 4 + kg) ^ rl7) << 3);
        #pragma unroll
        for (int f = 0; f < FN; ++f)
            boff[tt][f] = (wn + (f << 4) + rl) * 64 + (((tt * 4 + kg) ^ rl7) << 3);
    }

    f32x4 acc[4][FN];
    #pragma unroll
    for (int i = 0; i < 4; ++i)
        #pragma unroll
        for (int j = 0; j < FN; ++j) {
            acc[i][j][0] = 0.f; acc[i][j][1] = 0.f;
            acc[i][j][2] = 0.f; acc[i][j][3] = 0.f;
        }

    const int NT = K >> 6;
    #pragma unroll
    for (int i = 0; i < 4; ++i)  gl_lds16(gB[i], &Bs[0][cb[i]]);
    #pragma unroll
    for (int i = 0; i < NA; ++i) gl_lds16(gA[i], &As[0][ca[i]]);
    #pragma unroll
    for (int i = 0; i < 4; ++i)  gl_lds16(gB[i] + 64, &Bs[1][cb[i]]);
    #pragma unroll
    for (int i = 0; i < NA; ++i) gl_lds16(gA[i] + 64, &As[1][ca[i]]);

    for (int t = 0; t < NT; ++t) {
        const int cur = t & 1;
        if (t + 1 < NT) {
            if constexpr (BM == 128) asm volatile("s_waitcnt vmcnt(8)" ::: "memory");
            else                     asm volatile("s_waitcnt vmcnt(6)" ::: "memory");
        } else {
            asm volatile("s_waitcnt vmcnt(0)" ::: "memory");
        }
        __builtin_amdgcn_s_barrier();
        __builtin_amdgcn_sched_barrier(0);
        f16x8 av[2][4], bv[2][FN];
        #pragma unroll
        for (int tt = 0; tt < 2; ++tt) {
            #pragma unroll
            for (int f = 0; f < 4; ++f)
                av[tt][f] = *(const f16x8*)&As[cur][aoff[tt][f]];
            #pragma unroll
            for (int f = 0; f < FN; ++f)
                bv[tt][f] = *(const f16x8*)&Bs[cur][boff[tt][f]];
        }
        asm volatile("s_waitcnt lgkmcnt(0)" ::: "memory");
        __builtin_amdgcn_sched_barrier(0);
        __builtin_amdgcn_s_barrier();
        __builtin_amdgcn_sched_barrier(0);
        if (t + 2 < NT) {
            const int ko = (t + 2) << 6;
            #pragma unroll
            for (int i = 0; i < 4; ++i)  gl_lds16(gB[i] + ko, &Bs[cur][cb[i]]);
            #pragma unroll
            for (int i = 0; i < NA; ++i) gl_lds16(gA[i] + ko, &As[cur][ca[i]]);
        }
        #pragma unroll
        for (int fm = 0; fm < 4; ++fm)
            #pragma unroll
            for (int fn = 0; fn < FN; ++fn) {
                acc[fm][fn] = __builtin_amdgcn_mfma_f32_16x16x32_f16(av[0][fm], bv[0][fn], acc[fm][fn], 0, 0, 0);
                acc[fm][fn] = __builtin_amdgcn_mfma_f32_16x16x32_f16(av[1][fm], bv[1][fn], acc[fm][fn], 0, 0, 0);
            }
    }

    // ---- FFN1 colsum epilogue: Hpart[mb][n] = sum over block's 128 rows of relu(x) ----
    if (flags & 128) {
        if constexpr (BM == 128) {
            #pragma unroll
            for (int fn = 0; fn < FN; ++fn) {
                float p = 0.f;
                #pragma unroll
                for (int fm = 0; fm < 4; ++fm)
                    #pragma unroll
                    for (int r = 0; r < 4; ++r) p += fmaxf(acc[fm][fn][r], 0.f);
                p += __shfl_xor(p, 16);
                p += __shfl_xor(p, 32);
                if (kg == 0) hp[wave][fn * 16 + rl] = p;
            }
            __syncthreads();
            if (tid < 128) {
                int c = tid;
                float s = (c < 64) ? (hp[0][c] + hp[2][c]) : (hp[1][c - 64] + hp[3][c - 64]);
                hpart[(size_t)blockIdx.y * 4096 + n0 + c] = s;
            }
        }
        return;
    }

    // ---- standard epilogue: C/D layout col=lane&15, row=(lane>>4)*4+reg ----
    #pragma unroll
    for (int fm = 0; fm < 4; ++fm) {
        int row = m0 + wm + (fm << 4) + (kg << 2);
        #pragma unroll
        for (int fn = 0; fn < FN; ++fn) {
            int col = n0 + wn + (fn << 4) + rl;
            if (flags & 64) {
                ushort4 u;
                u.x = f2h(acc[fm][fn][0]); u.y = f2h(acc[fm][fn][1]);
                u.z = f2h(acc[fm][fn][2]); u.w = f2h(acc[fm][fn][3]);
                size_t a = ((size_t)((row >> 10) * 16 + (col >> 6)) * 64 + (col & 63)) * 1024 + (row & 1023);
                *(ushort4*)(outh + a) = u;
                continue;
            }
            #pragma unroll
            for (int r = 0; r < 4; ++r) {
                float x = acc[fm][fn][r];
                int rr = row + r;
                if (flags & 32) {
                    if (rr < 4096) outh[(size_t)rr * 1024 + col] = f2h(x);                      // Qh
                    else           outh2[(size_t)(rr - 4096) * 1024 + (col - 1024)] = f2h(x);   // Kh16
                } else {
                    size_t idx = (size_t)rr * N + col;
                    if (flags & 1)  x = fmaxf(x, 0.f);
                    if (flags & 8)  outf[idx] = x;
                    if (flags & 16) outh[idx] = f2h(x);
                }
            }
        }
    }
}

// ---------------- MFMA flash attention (swapped QK, fp16) ----------------
__global__ __launch_bounds__(256) void attn_mfma(
    const unsigned short* __restrict__ Qh,
    const unsigned short* __restrict__ Kh,
    const unsigned short* __restrict__ Vt,
    unsigned short* __restrict__ q16,
    const int* __restrict__ qlens, const int* __restrict__ klens)
{
    __shared__ __align__(16) unsigned short KS[4096];
    __shared__ __align__(16) unsigned short VtS[4096];
    __shared__ __align__(16) unsigned short Pl[4][1152];

    const int tid = threadIdx.x;
    const int bh = blockIdx.x & 63;
    const int qt = blockIdx.x >> 6;
    const int b = bh >> 4, h = bh & 15;
    const int qbase = qt * 64;
    const int qlen = qlens[b], klen = klens[b];
    if (qbase >= qlen) return;

    const int lane = tid & 63, wq = tid >> 6;
    const int rl = lane & 15, kg = lane >> 4, rl7 = lane & 7;
    const int gq = qbase + wq * 16 + rl;

    f16x8 qb[2];
    {
        const unsigned short* p1 = Qh + (size_t)(b * 1024 + gq) * 1024 + h * 64 + kg * 8;
        qb[0] = *(const f16x8*)p1;  qb[1] = *(const f16x8*)(p1 + 32);
    }

    const unsigned short* gK[2]; const unsigned short* gV[2];
    int cs[2];
    #pragma unroll
    for (int i = 0; i < 2; ++i) {
        int c = i * 256 + tid;
        int row = c >> 3, ch = (c & 7) ^ (row & 7);
        cs[i] = c * 8;
        gK[i] = Kh + (size_t)(b * 1024 + row) * 1024 + h * 64 + ch * 8;
        gV[i] = Vt + (size_t)(bh * 64 + row) * 1024 + ch * 8;
    }

    int akoff[4][2];
    #pragma unroll
    for (int mf = 0; mf < 4; ++mf)
        #pragma unroll
        for (int kh = 0; kh < 2; ++kh)
            akoff[mf][kh] = (mf * 16 + rl) * 64 + (((kg + 4 * kh) ^ rl7) << 3);

    f32x4 o[4];
    #pragma unroll
    for (int i = 0; i < 4; ++i) { o[i][0]=0.f; o[i][1]=0.f; o[i][2]=0.f; o[i][3]=0.f; }
    float m_run = -3.0e38f, l_run = 0.f;
    const int nt = (klen == 1) ? (T_ / 64) : ((klen + 63) >> 6);

    for (int kb = 0; kb < nt; ++kb) {
        const int kbase = kb * 64;
        const size_t koff = (size_t)kbase * 1024;
        gl_lds16(gK[0] + koff, &KS[cs[0]]);
        gl_lds16(gK[1] + koff, &KS[cs[1]]);
        gl_lds16(gV[0] + kbase, &VtS[cs[0]]);
        gl_lds16(gV[1] + kbase, &VtS[cs[1]]);
        __syncthreads();

        float v[4][4];
        __builtin_amdgcn_s_setprio(1);
        #pragma unroll
        for (int mf = 0; mf < 4; ++mf) {
            f32x4 s; s[0]=0.f; s[1]=0.f; s[2]=0.f; s[3]=0.f;
            f16x8 a0 = *(const f16x8*)&KS[akoff[mf][0]];
            f16x8 a1 = *(const f16x8*)&KS[akoff[mf][1]];
            s = __builtin_amdgcn_mfma_f32_16x16x32_f16(a0, qb[0], s, 0, 0, 0);
            s = __builtin_amdgcn_mfma_f32_16x16x32_f16(a1, qb[1], s, 0, 0, 0);
            #pragma unroll
            for (int r = 0; r < 4; ++r) {
                int gk = kbase + mf * 16 + kg * 4 + r;
                float x = s[r] * 0.125f;
                if (gk >= klen || gk == gq) x = NEG_;
                v[mf][r] = x;
            }
        }
        __builtin_amdgcn_s_setprio(0);
        float mt = -3.0e38f;
        #pragma unroll
        for (int mf = 0; mf < 4; ++mf)
            #pragma unroll
            for (int r = 0; r < 4; ++r) mt = fmaxf(mt, v[mf][r]);
        mt = fmaxf(mt, __shfl_xor(mt, 16));
        mt = fmaxf(mt, __shfl_xor(mt, 32));
        float mnew = fmaxf(m_run, mt);
        float fac = __expf(m_run - mnew);
        float sum = 0.f;
        #pragma unroll
        for (int mf = 0; mf < 4; ++mf) {
            ushort4 pb;
            pb.x = f2h(__expf(v[mf][0] - mnew));
            pb.y = f2h(__expf(v[mf][1] - mnew));
            pb.z = f2h(__expf(v[mf][2] - mnew));
            pb.w = f2h(__expf(v[mf][3] - mnew));
            sum += h2f(pb.x) + h2f(pb.y) + h2f(pb.z) + h2f(pb.w);
            *(ushort4*)&Pl[wq][rl * 72 + mf * 16 + kg * 4] = pb;
        }
        sum += __shfl_xor(sum, 16);
        sum += __shfl_xor(sum, 32);
        l_run = l_run * fac + sum;
        m_run = mnew;
        #pragma unroll
        for (int i = 0; i < 4; ++i) {
            o[i][0] *= fac; o[i][1] *= fac; o[i][2] *= fac; o[i][3] *= fac;
        }
        f16x8 bp0 = *(const f16x8*)&Pl[wq][rl * 72 + kg * 8];
        f16x8 bp1 = *(const f16x8*)&Pl[wq][rl * 72 + 32 + kg * 8];
        __builtin_amdgcn_s_setprio(1);
        #pragma unroll
        for (int dmf = 0; dmf < 4; ++dmf) {
            f16x8 a0 = *(const f16x8*)&VtS[akoff[dmf][0]];
            f16x8 a1 = *(const f16x8*)&VtS[akoff[dmf][1]];
            o[dmf] = __builtin_amdgcn_mfma_f32_16x16x32_f16(a0, bp0, o[dmf], 0, 0, 0);
            o[dmf] = __builtin_amdgcn_mfma_f32_16x16x32_f16(a1, bp1, o[dmf], 0, 0, 0);
        }
        __builtin_amdgcn_s_setprio(0);
        __syncthreads();
    }

    float invl = (gq < qlen) ? (1.f / l_run) : 0.f;
    #pragma unroll
    for (int dmf = 0; dmf < 4; ++dmf)
        #pragma unroll
        for (int r = 0; r < 4; ++r) {
            int dh = dmf * 16 + kg * 4 + r;
            size_t a = (size_t)(b * 1024 + gq) * 1024 + h * 64 + dh;
            q16[a] = f2h(o[dmf][r] * invl + h2f(q16[a]));
        }
}

// ---------------- mean over T of fp16 [4][1024][1024] -> f32 [4][1024] ----------------
__global__ __launch_bounds__(256) void mean16(const unsigned short* __restrict__ X,
                                              float* __restrict__ out, int Xdim)
{
    __shared__ float red[4][128];
    int tid = threadIdx.x;
    int b = blockIdx.y;
    int dbase = blockIdx.x * 128;
    int tq = tid >> 6, dd = tid & 63;
    int d = dbase + dd * 2;
    const unsigned short* p = X + ((size_t)b * T_ + tq * 256) * Xdim + d;
    float s0 = 0.f, s1 = 0.f;
    for (int t = 0; t < 256; ++t) {
        ushort2 v = *(const ushort2*)(p + (size_t)t * Xdim);
        s0 += h2f(v.x); s1 += h2f(v.y);
    }
    red[tq][dd*2] = s0; red[tq][dd*2 + 1] = s1;
    __syncthreads();
    if (tq == 0) {
        float a = red[0][dd*2] + red[1][dd*2] + red[2][dd*2] + red[3][dd*2];
        float c = red[0][dd*2+1] + red[1][dd*2+1] + red[2][dd*2+1] + red[3][dd*2+1];
        out[(size_t)b * Xdim + d]     = a * (1.f/1024.f);
        out[(size_t)b * Xdim + d + 1] = c * (1.f/1024.f);
    }
}

// ---- partial (hm_reduce fused): Pout[jy][b][d] = sum_{j in 128-chunk jy} Hm[b][j]*fw2[j][d] ----
__global__ __launch_bounds__(256) void final_partial(const float* __restrict__ Hpart,
                                                     const float* __restrict__ fw2,
                                                     float* __restrict__ Pout)
{
    __shared__ float red[4][4][64];
    __shared__ float hm[4][128];
    int tid = threadIdx.x;
    // build the Hm tile for this j-chunk: Hm[b][j] = sum_i Hpart[b*8+i][j] / 1024
    #pragma unroll
    for (int s = 0; s < 2; ++s) {
        int idx = s * 256 + tid;          // 512 entries
        int bb = idx >> 7, jl = idx & 127;
        int j = blockIdx.y * 128 + jl;
        float acc = 0.f;
        #pragma unroll
        for (int i = 0; i < 8; ++i)
            acc += Hpart[((size_t)(bb * 8 + i)) * 4096 + j];
        hm[bb][jl] = acc * (1.f / 1024.f);
    }
    __syncthreads();
    int dd = tid & 63;
    int d = blockIdx.x * 64 + dd;
    int jq = tid >> 6;
    float s4[4] = {0.f, 0.f, 0.f, 0.f};
    for (int jj = 0; jj < 32; ++jj) {
        int jl = jq * 32 + jj;
        int j = blockIdx.y * 128 + jl;
        float wv = fw2[(size_t)j * 1024 + d];
        s4[0] += hm[0][jl] * wv;
        s4[1] += hm[1][jl] * wv;
        s4[2] += hm[2][jl] * wv;
        s4[3] += hm[3][jl] * wv;
    }
    #pragma unroll
    for (int bb = 0; bb < 4; ++bb) red[jq][bb][dd] = s4[bb];
    __syncthreads();
    if (jq == 0) {
        #pragma unroll
        for (int bb = 0; bb < 4; ++bb) {
            float tot = red[0][bb][dd] + red[1][bb][dd] + red[2][bb][dd] + red[3][bb][dd];
            Pout[((size_t)blockIdx.y * 4 + bb) * 1024 + d] = tot;
        }
    }
}

// ---------------- out[b][d] = Mres[b][d] + sum_{jy<32} Pout[jy][b][d] ----------------
__global__ __launch_bounds__(256) void reduce_out(const float* __restrict__ Mres,
                                                  const float* __restrict__ Pout,
                                                  float* __restrict__ out)
{
    int idx = blockIdx.x * 256 + threadIdx.x;
    int b = idx >> 10, d = idx & 1023;
    float s = Mres[(size_t)b * 1024 + d];
    #pragma unroll
    for (int jy = 0; jy < 32; ++jy)
        s += Pout[((size_t)jy * 4 + b) * 1024 + d];
    out[(size_t)b * 1024 + d] = s;
}

extern "C" void kernel_launch(void* const* d_in, const int* in_sizes, int n_in,
                              void* d_out, int out_size, void* d_ws, size_t ws_size,
                              hipStream_t stream)
{
    const float* queries = (const float*)d_in[0];
    const int*   qlens   = (const int*)d_in[2];
    const int*   klens   = (const int*)d_in[3];
    const float* pe_q    = (const float*)d_in[4];
    const float* pe_k    = (const float*)d_in[5];
    const float* Wq      = (const float*)d_in[6];
    const float* Wk      = (const float*)d_in[7];
    const float* Wv      = (const float*)d_in[8];
    const float* fw1     = (const float*)d_in[9];
    const float* fw2     = (const float*)d_in[10];
    float* out = (float*)d_out;

    // arena (MB offsets), peak ~57 MB, no overlays except q16 = A2 rows 0..4095
    char* w = (char*)d_ws;
    unsigned short* Qh   = (unsigned short*)(w);                  // [0,8)
    unsigned short* A2   = (unsigned short*)(w + (8ll  << 20));   // [8,24)  8192x1024 fp16
    unsigned short* q16  = A2;                                    // [8,16)
    unsigned short* Kh16 = (unsigned short*)(w + (24ll << 20));   // [24,32)
    unsigned short* B2   = (unsigned short*)(w + (32ll << 20));   // [32,36)
    unsigned short* WvT  = (unsigned short*)(w + (36ll << 20));   // [36,38)
    unsigned short* Vt   = (unsigned short*)(w + (38ll << 20));   // [38,46)
    unsigned short* fw1T = (unsigned short*)(w + (46ll << 20));   // [46,54)
    float*          Hpart= (float*)(w + (54ll << 20));            // 512 KB: [32 mb][4096 n]
    float*          Mres = (float*)(w + (55ll << 20));            // 16 KB
    float*          Pout = (float*)(w + (56ll << 20));            // 512 KB

    // 1) conversions
    conv_a <<<8192, 256, 0, stream>>>(queries, pe_q, pe_k, A2);
    conv_w2<<<dim3(32, 32, 2), 256, 0, stream>>>(Wq, Wk, B2);
    conv_wT<<<dim3(32, 32), 256, 0, stream>>>(Wv, WvT, 1024, 1024);
    conv_wT<<<dim3(128, 32), 256, 0, stream>>>(fw1, fw1T, 1024, 4096);
    // 2) stacked [Q|K] GEMM: M=8192 (q_in rows | k_in rows), N=2048, K=1024 fp16, len-skip
    gemm_mfma<128><<<dim3(16, 64), 256, 0, stream>>>(
        A2, 1024, B2, 1024, 1024,
        nullptr, Qh, Kh16, 2048, 32, qlens, klens, nullptr);
    // 3) V = Kh16 @ Wv, stored fp16 transposed Vt[b,h][dh][t]  (len-skip, klen==1 keeps all)
    gemm_mfma<64><<<dim3(8, 64), 256, 0, stream>>>(
        Kh16, 1024, WvT, 1024, 1024,
        nullptr, Vt, nullptr, 1024, 64 | 256, nullptr, klens, nullptr);
    // 4) MFMA attention + residual -> q16 in place
    attn_mfma<<<1024, 256, 0, stream>>>(Qh, Kh16, Vt, q16, qlens, klens);
    // 5) FFN1 fused colsum: Hpart[mb][n] = sum_rows relu(res @ fw1)
    gemm_mfma<128><<<dim3(32, 32), 256, 0, stream>>>(
        q16, 1024, fw1T, 1024, 1024,
        nullptr, nullptr, nullptr, 4096, 128, nullptr, nullptr, Hpart);
    // 6) means + final: out = mean_t(res) + mean_t(h1) @ fw2
    mean16<<<dim3(8, 4), 256, 0, stream>>>(q16, Mres, 1024);
    final_partial<<<dim3(16, 32), 256, 0, stream>>>(Hpart, fw2, Pout);
    reduce_out<<<16, 256, 0, stream>>>(Mres, Pout, out);
}